// Round 1
// baseline (2784.064 us; speedup 1.0000x reference)
//
#include <hip/hip_runtime.h>

// ============================================================================
// MUCRP_17265768530653 — cross-domain VAE forward on MI355X (gfx950)
// Round 1: correctness-first full pipeline.
//  - all big GEMMs via bf16 MFMA 16x16x32, f32 accumulate
//  - encoder GEMMs: split-K(32) -> f32 partials -> reduce+bias+relu
//  - FGW: 10 outer iters x (2 x 1024^3 bf16 GEMM + 11 matvec launches)
//  - weights pre-transposed to bf16 [N][K] so LDS staging is contiguous
// ============================================================================

#define DEVI __device__ __forceinline__

typedef __attribute__((ext_vector_type(4))) float  f32x4;
typedef __attribute__((ext_vector_type(4))) short  s16x4;
typedef __attribute__((ext_vector_type(8))) short  s16x8;
typedef __attribute__((ext_vector_type(8))) __bf16 bf16x8;

DEVI short f2bf(float f) {              // RNE f32 -> bf16 (bits)
  unsigned u = __float_as_uint(f);
  u += 0x7fffu + ((u >> 16) & 1u);
  return (short)(u >> 16);
}

DEVI f32x4 mfma16(bf16x8 a, bf16x8 b, f32x4 c) {
  return __builtin_amdgcn_mfma_f32_16x16x32_bf16(a, b, c, 0, 0, 0);
}

// ---------------------------------------------------------------------------
// Generic tiled MFMA GEMM.  A: f32 or bf16 row-major [M][lda] (k fast).
// B: bf16 stored TRANSPOSED [N][ldbt] (k fast).  Wave tile 32x64 (2x4 frags).
// ---------------------------------------------------------------------------
struct GemmArgs {
  const float* Af;
  const unsigned short* Ab;
  const unsigned short* Bt;
  float* outF;
  unsigned short* outB;
  const float* bias;
  const float* cpp;
  const float* f1;
  const float* f2;
  const float* tranF;
  unsigned* mx;
  float* loss;
  float* partials;
  int M, N, K;
  int lda, ldbt, ldc;
  int totSteps, nSplits;
};

enum { EPI_PARTIAL, EPI_BIAS, EPI_BF16, EPI_COST, EPI_LOSS };

template<int BM, int BN, int WR, int WC, int AF32, int EPI>
__global__ __launch_bounds__(WR*WC*64)
void k_gemm(GemmArgs g)
{
  constexpr int BK = 64, BKP = 72;      // +8 bf16 pad: 2-way LDS aliasing only
  constexpr int NT = WR * WC * 64;
  __shared__ short As[BM * BKP];
  __shared__ short Bs[BN * BKP];

  const int m0 = blockIdx.x * BM;
  int n0 = 0, kb0 = 0, kb1 = g.K, split = 0;
  if constexpr (EPI == EPI_PARTIAL) {   // split-K over blockIdx.y
    split = blockIdx.y;
    int s0 = (split * g.totSteps) / g.nSplits;
    int s1 = ((split + 1) * g.totSteps) / g.nSplits;
    kb0 = s0 * BK;
    kb1 = s1 * BK; if (kb1 > g.K) kb1 = g.K;
  } else {
    n0 = blockIdx.y * BN;
  }
  const int tid  = threadIdx.x;
  const int lane = tid & 63;
  const int wv   = tid >> 6;
  const int wr   = wv % WR;
  const int wc   = wv / WR;

  f32x4 acc[2][4];
  #pragma unroll
  for (int i = 0; i < 2; ++i)
    #pragma unroll
    for (int j = 0; j < 4; ++j) acc[i][j] = f32x4{0.f, 0.f, 0.f, 0.f};

  for (int kb = kb0; kb < kb1; kb += BK) {
    // ---- stage A tile
    if constexpr (AF32) {
      constexpr int NV = BM * BK / 4;
      #pragma unroll
      for (int i = 0; i < NV / NT; ++i) {
        int idx = tid + NT * i;
        int r = idx >> 4, q = idx & 15;
        int k = kb + 4 * q;
        f32x4 v = f32x4{0.f, 0.f, 0.f, 0.f};
        if (k < kb1) v = *(const f32x4*)(g.Af + (size_t)(m0 + r) * g.lda + k);
        s16x4 s;
        s.x = f2bf(v.x); s.y = f2bf(v.y); s.z = f2bf(v.z); s.w = f2bf(v.w);
        *(s16x4*)&As[r * BKP + 4 * q] = s;
      }
    } else {
      constexpr int NV = BM * BK / 8;
      #pragma unroll
      for (int i = 0; i < NV / NT; ++i) {
        int idx = tid + NT * i;
        int r = idx >> 3, q = idx & 7;
        int k = kb + 8 * q;
        s16x8 v{};
        if (k < kb1) v = *(const s16x8*)(g.Ab + (size_t)(m0 + r) * g.lda + k);
        *(s16x8*)&As[r * BKP + 8 * q] = v;
      }
    }
    // ---- stage B tile (bf16 [N][K])
    {
      constexpr int NV = BN * BK / 8;
      #pragma unroll
      for (int i = 0; i < NV / NT; ++i) {
        int idx = tid + NT * i;
        int r = idx >> 3, q = idx & 7;
        int k = kb + 8 * q;
        s16x8 v{};
        if ((n0 + r) < g.N && k < kb1)
          v = *(const s16x8*)(g.Bt + (size_t)(n0 + r) * g.ldbt + k);
        *(s16x8*)&Bs[r * BKP + 8 * q] = v;
      }
    }
    __syncthreads();
    #pragma unroll
    for (int s = 0; s < 2; ++s) {       // two K=32 slabs per BK=64 step
      const int ko = 32 * s + 8 * (lane >> 4);
      bf16x8 a0 = *(const bf16x8*)&As[(wr * 32 +      (lane & 15)) * BKP + ko];
      bf16x8 a1 = *(const bf16x8*)&As[(wr * 32 + 16 + (lane & 15)) * BKP + ko];
      #pragma unroll
      for (int fn = 0; fn < 4; ++fn) {
        bf16x8 b = *(const bf16x8*)&Bs[(wc * 64 + fn * 16 + (lane & 15)) * BKP + ko];
        acc[0][fn] = mfma16(a0, b, acc[0][fn]);
        acc[1][fn] = mfma16(a1, b, acc[1][fn]);
      }
    }
    __syncthreads();
  }

  // ---- epilogue.  C/D layout (verified): col = lane&15, row = (lane>>4)*4+p
  float lred = 0.f;
  #pragma unroll
  for (int fm = 0; fm < 2; ++fm) {
    #pragma unroll
    for (int fn = 0; fn < 4; ++fn) {
      #pragma unroll
      for (int p = 0; p < 4; ++p) {
        int gm = m0 + wr * 32 + fm * 16 + (lane >> 4) * 4 + p;
        int gn = n0 + wc * 64 + fn * 16 + (lane & 15);
        float v = acc[fm][fn][p];
        if constexpr (EPI == EPI_PARTIAL) {
          g.partials[((size_t)split * g.M + gm) * 256 + gn] = v;
        } else if constexpr (EPI == EPI_BIAS) {
          if (gn < g.N) g.outF[(size_t)gm * g.ldc + gn] = v + g.bias[gn];
        } else if constexpr (EPI == EPI_BF16) {
          g.outB[(size_t)gm * g.ldc + gn] = (unsigned short)f2bf(v);
        } else {
          float cost = 0.1f * (g.f1[gm] + g.f2[gn] - 2.f * v)
                     + 0.9f * g.cpp[(size_t)gm * 1024 + gn];
          if constexpr (EPI == EPI_COST) {
            g.outF[(size_t)gm * 1024 + gn] = cost;
            lred = fmaxf(lred, fabsf(cost));
          } else {
            lred += cost * g.tranF[(size_t)gm * 1024 + gn];
          }
        }
      }
    }
  }
  if constexpr (EPI == EPI_COST || EPI == EPI_LOSS) {
    #pragma unroll
    for (int o = 32; o; o >>= 1) {
      float t = __shfl_xor(lred, o, 64);
      lred = (EPI == EPI_COST) ? fmaxf(lred, t) : lred + t;
    }
    __syncthreads();
    float* red = (float*)As;
    if (lane == 0) red[wv] = lred;
    __syncthreads();
    if (tid == 0) {
      float t = red[0];
      #pragma unroll
      for (int i = 1; i < NT / 64; ++i)
        t = (EPI == EPI_COST) ? fmaxf(t, red[i]) : t + red[i];
      if constexpr (EPI == EPI_COST) atomicMax(g.mx, __float_as_uint(t));
      else atomicAdd(g.loss, t);
    }
  }
}

// ---------------------------------------------------------------------------
// f32 [R][C] -> bf16 [C][R] tiled transpose (weight prep, runs once per call)
// ---------------------------------------------------------------------------
__global__ void k_transpose(const float* in, unsigned short* out, int R, int C)
{
  __shared__ float t[64][65];
  const int r0 = blockIdx.x * 64, c0 = blockIdx.y * 64;
  const int tid = threadIdx.x;
  #pragma unroll
  for (int i = 0; i < 16; ++i) {
    int idx = tid + 256 * i;
    int r = idx >> 6, c = idx & 63;
    float v = 0.f;
    if ((r0 + r) < R && (c0 + c) < C) v = in[(size_t)(r0 + r) * C + (c0 + c)];
    t[r][c] = v;
  }
  __syncthreads();
  #pragma unroll
  for (int i = 0; i < 16; ++i) {
    int idx = tid + 256 * i;
    int c = idx >> 6, r = idx & 63;
    if ((c0 + c) < C && (r0 + r) < R)
      out[(size_t)(c0 + c) * R + (r0 + r)] = (unsigned short)f2bf(t[r][c]);
  }
}

__global__ void k_reduce_relu(const float* partials, const float* bias, float* h, int ns)
{
  int idx = blockIdx.x * 256 + threadIdx.x;   // over 1024*256
  float s = bias[idx & 255];
  for (int p = 0; p < ns; ++p) s += partials[(size_t)p * (1024 * 256) + idx];
  h[idx] = fmaxf(s, 0.f);
}

// h[256] -> mu[64], logvar[64], z = mu + eps*exp(0.5*lv).  One row per block.
__global__ void k_enc_head(const float* h, const float* W21, const float* b21,
                           const float* W22, const float* b22, const float* eps,
                           float* muO, float* lvO, float* zO)
{
  __shared__ float hrow[256];
  __shared__ float res[128];
  const int i = blockIdx.x;
  const int t = threadIdx.x;                  // 128
  hrow[t]       = h[(size_t)i * 256 + t];
  hrow[t + 128] = h[(size_t)i * 256 + t + 128];
  __syncthreads();
  const int c = t & 63;
  const float* W = (t < 64) ? W21 : W22;
  float a = (t < 64) ? b21[c] : b22[c];
  #pragma unroll 8
  for (int j = 0; j < 256; ++j) a += hrow[j] * W[j * 64 + c];
  res[t] = a;
  __syncthreads();
  if (t < 64) {
    float mu = res[t], lv = res[64 + t];
    muO[(size_t)i * 64 + t] = mu;
    lvO[(size_t)i * 64 + t] = lv;
    zO[(size_t)i * 64 + t]  = mu + eps[(size_t)i * 64 + t] * expf(0.5f * lv);
  }
}

// hd[256] = relu(z[64] @ W3 + b3).  One row per block.
__global__ void k_dec_head(const float* z, const float* W3, const float* b3, float* hd)
{
  __shared__ float zrow[64];
  const int i = blockIdx.x;
  const int t = threadIdx.x;                  // 256
  if (t < 64) zrow[t] = z[(size_t)i * 64 + t];
  __syncthreads();
  float a = b3[t];
  #pragma unroll
  for (int d = 0; d < 64; ++d) a += zrow[d] * W3[d * 256 + t];
  hd[(size_t)i * 256 + t] = fmaxf(a, 0.f);
}

// ---------------------------------------------------------------------------
// _distance_gmm 64x64 tile: dist2(mu) + dist2(exp(.5 lv)) + 1e-6.
// Two passes (mu, sigma) reusing the same LDS.  Optionally f_row = sum c^2/1024.
// ---------------------------------------------------------------------------
template<int WRITE_BF, int DO_F>
__global__ void k_dist(const float* xmu, const float* xlv, const float* ymu, const float* ylv,
                       unsigned short* outB, float* outF, float* frow)
{
  __shared__ float SX[64 * 68];
  __shared__ float SY[64 * 68];
  const int r0 = blockIdx.x * 64, c0 = blockIdx.y * 64;
  const int t = threadIdx.x;                  // 256
  const int rr = t >> 2;
  const int c4 = (t & 3) * 16;
  float acc[16];
  #pragma unroll
  for (int i = 0; i < 16; ++i) acc[i] = 0.f;

  for (int pass = 0; pass < 2; ++pass) {
    __syncthreads();
    #pragma unroll
    for (int i = 0; i < 16; ++i) {
      int idx = t + 256 * i;
      int r = idx >> 6, d = idx & 63;
      float vx, vy;
      if (pass == 0) {
        vx = xmu[(size_t)(r0 + r) * 64 + d];
        vy = ymu[(size_t)(c0 + r) * 64 + d];
      } else {
        vx = expf(0.5f * xlv[(size_t)(r0 + r) * 64 + d]);
        vy = expf(0.5f * ylv[(size_t)(c0 + r) * 64 + d]);
      }
      SX[r * 68 + d] = vx;
      SY[r * 68 + d] = vy;
    }
    __syncthreads();
    #pragma unroll
    for (int i = 0; i < 16; ++i) {
      int cc = c4 + i;
      float s = 0.f;
      #pragma unroll
      for (int d4 = 0; d4 < 16; ++d4) {
        f32x4 a = *(const f32x4*)&SX[rr * 68 + 4 * d4];
        f32x4 b = *(const f32x4*)&SY[cc * 68 + 4 * d4];
        f32x4 df = a - b;
        s += df.x * df.x + df.y * df.y + df.z * df.z + df.w * df.w;
      }
      acc[i] += s;
    }
  }
  float fpart = 0.f;
  #pragma unroll
  for (int i = 0; i < 16; ++i) {
    int cc = c4 + i;
    float val = acc[i] + 1e-6f;
    if constexpr (WRITE_BF) outB[(size_t)(r0 + rr) * 1024 + (c0 + cc)] = (unsigned short)f2bf(val);
    else                    outF[(size_t)(r0 + rr) * 1024 + (c0 + cc)] = val;
    if constexpr (DO_F) fpart += val * val;
  }
  if constexpr (DO_F) {
    fpart += __shfl_xor(fpart, 1, 64);
    fpart += __shfl_xor(fpart, 2, 64);
    if ((t & 3) == 0) atomicAdd(frow + (r0 + rr), fpart * (1.f / 1024.f));
  }
}

// K = exp(-cost/mx) * tran ; also write K^T (tiled)
__global__ void k_kbuild(const float* cost, const float* tran, const unsigned* mxbits,
                         float* K, float* KT)
{
  __shared__ float t[64][65];
  const int r0 = blockIdx.x * 64, c0 = blockIdx.y * 64;
  const int tid = threadIdx.x;
  const float inv = 1.f / __uint_as_float(*mxbits);
  #pragma unroll
  for (int i = 0; i < 16; ++i) {
    int idx = tid + 256 * i;
    int r = idx >> 6, c = idx & 63;
    size_t o = (size_t)(r0 + r) * 1024 + (c0 + c);
    float v = expf(-cost[o] * inv) * tran[o];
    K[o] = v;
    t[r][c] = v;
  }
  __syncthreads();
  #pragma unroll
  for (int i = 0; i < 16; ++i) {
    int idx = tid + 256 * i;
    int c = idx >> 6, r = idx & 63;
    KT[(size_t)(c0 + c) * 1024 + (r0 + r)] = t[r][c];
  }
}

// y_i = p / (M[i,:] . x).  4 rows per block (one per wave).
__global__ void k_matvec(const float* M, const float* x, float* y, float pval)
{
  const int r = blockIdx.x * 4 + (threadIdx.x >> 6);
  const int lane = threadIdx.x & 63;
  const f32x4* row = (const f32x4*)(M + (size_t)r * 1024);
  const f32x4* xv  = (const f32x4*)x;
  float s = 0.f;
  #pragma unroll
  for (int q = 0; q < 4; ++q) {
    f32x4 a = row[lane + 64 * q];
    f32x4 b = xv [lane + 64 * q];
    s += a.x * b.x + a.y * b.y + a.z * b.z + a.w * b.w;
  }
  #pragma unroll
  for (int o = 32; o; o >>= 1) s += __shfl_xor(s, o, 64);
  if (lane == 0) y[r] = pval / s;
}

// tran = (dual (x) b) * K ; also emit tran^T in bf16 for the next GEMM1
__global__ void k_tranupd(const float* K, const float* dual, const float* bv,
                          float* tran, unsigned short* tranT)
{
  __shared__ float t[64][65];
  const int r0 = blockIdx.x * 64, c0 = blockIdx.y * 64;
  const int tid = threadIdx.x;
  #pragma unroll
  for (int i = 0; i < 16; ++i) {
    int idx = tid + 256 * i;
    int r = idx >> 6, c = idx & 63;
    size_t o = (size_t)(r0 + r) * 1024 + (c0 + c);
    float v = dual[r0 + r] * bv[c0 + c] * K[o];
    tran[o] = v;
    t[r][c] = v;
  }
  __syncthreads();
  #pragma unroll
  for (int i = 0; i < 16; ++i) {
    int idx = tid + 256 * i;
    int c = idx >> 6, r = idx & 63;
    tranT[(size_t)(c0 + c) * 1024 + (r0 + r)] = (unsigned short)f2bf(t[r][c]);
  }
}

__global__ void k_init_small(float* f1, float* f2, unsigned* mx, unsigned* nanflag,
                             float* cyc, float* ga, float* gb, float* al)
{
  int t = threadIdx.x;                        // 1024
  f1[t] = 0.f; f2[t] = 0.f;
  if (t < 16) mx[t] = 0u;
  if (t == 0) { *nanflag = 0u; cyc[0] = 0.f; cyc[1] = 0.f; *ga = 0.f; *gb = 0.f; *al = 0.f; }
}

__global__ void k_tran_init(float* tran, unsigned short* tranT, float* dual)
{
  int idx = blockIdx.x * 256 + threadIdx.x;
  const float v = 1.f / (1024.f * 1024.f);
  tran[idx]  = v;
  tranT[idx] = (unsigned short)f2bf(v);
  if (idx < 1024) dual[idx] = 1.f / 1024.f;
}

__global__ void k_nancheck(const float* tran, unsigned* flag)
{
  int idx = blockIdx.x * 256 + threadIdx.x;
  float v = tran[idx];
  if (v != v) atomicOr(flag, 1u);
}

__global__ void k_nanfix(float* tran, unsigned short* tranT, const unsigned* flag)
{
  if (*flag == 0u) return;
  int idx = blockIdx.x * 256 + threadIdx.x;
  const float v = 1.f / (1024.f * 1024.f);
  tran[idx]  = v;
  tranT[idx] = (unsigned short)f2bf(v);
}

// GMM KL row contribution; one wave per batch row, atomicAdd into scalar.
__global__ void k_gmm(const float* z, const float* mu, const float* lv,
                      const float* pmu, const float* plv, float* outsc)
{
  const int i = blockIdx.x;
  const int d = threadIdx.x;                  // 64
  const float zd = z[(size_t)i * 64 + d];
  const float m  = mu[(size_t)i * 64 + d];
  const float l  = lv[(size_t)i * 64 + d];
  float t = l + (zd - m) * (zd - m) * expf(-l);
  #pragma unroll
  for (int o = 32; o; o >>= 1) t += __shfl_xor(t, o, 64);
  const float C0 = 64.f * 1.8378770664093453f;     // D*log(2*pi)
  float logq = -0.5f * (C0 + t);
  float lp[20];
  #pragma unroll
  for (int k = 0; k < 20; ++k) {
    float pm = pmu[k * 64 + d], pl = plv[k * 64 + d];
    float u = pl + (zd - pm) * (zd - pm) * expf(-pl);
    #pragma unroll
    for (int o = 32; o; o >>= 1) u += __shfl_xor(u, o, 64);
    lp[k] = -0.5f * (C0 + u);
  }
  float mx = lp[0];
  #pragma unroll
  for (int k = 1; k < 20; ++k) mx = fmaxf(mx, lp[k]);
  float s = 0.f;
  #pragma unroll
  for (int k = 0; k < 20; ++k) s += expf(lp[k] - mx);
  float logp = mx + logf(s) - 2.9957322735539909f; // log(20)
  if (d == 0) atomicAdd(outsc, logq - logp);
}

__global__ void k_sqdiff(const float* a, const float* b, float* slot)
{
  __shared__ float red[4];
  int idx = blockIdx.x * 256 + threadIdx.x;   // 65536 total
  float d = a[idx] - b[idx];
  d = d * d;
  #pragma unroll
  for (int o = 32; o; o >>= 1) d += __shfl_xor(d, o, 64);
  int lane = threadIdx.x & 63, wv = threadIdx.x >> 6;
  if (lane == 0) red[wv] = d;
  __syncthreads();
  if (threadIdx.x == 0) atomicAdd(slot, red[0] + red[1] + red[2] + red[3]);
}

__global__ void k_finish(const float* slots, float* o1, float* o2)
{
  if (threadIdx.x == 0) { *o1 = sqrtf(slots[0]); *o2 = sqrtf(slots[1]); }
}

// ---------------------------------------------------------------------------
// launch helpers
// ---------------------------------------------------------------------------
static void launch_enc(const float* A, int lda, const unsigned short* Bt, int Kdim,
                       float* partials, hipStream_t s)
{
  GemmArgs g{};
  g.Af = A; g.Bt = Bt; g.partials = partials;
  g.M = 1024; g.N = 256; g.K = Kdim; g.lda = lda; g.ldbt = Kdim;
  g.totSteps = (Kdim + 63) / 64; g.nSplits = 32;
  k_gemm<128, 256, 4, 4, 1, EPI_PARTIAL><<<dim3(8, 32), 1024, 0, s>>>(g);
}

static void launch_dec(const float* hd, const unsigned short* W4t, const float* bias,
                       int N, float* outp, hipStream_t s)
{
  GemmArgs g{};
  g.Af = hd; g.Bt = W4t; g.outF = outp; g.bias = bias;
  g.M = 1024; g.N = N; g.K = 256; g.lda = 256; g.ldbt = 256; g.ldc = N;
  k_gemm<128, 256, 4, 4, 1, EPI_BIAS><<<dim3(8, (N + 255) / 256), 1024, 0, s>>>(g);
}

static void launch_g1(const unsigned short* cpostB, const unsigned short* tranT,
                      unsigned short* U, hipStream_t s)
{
  GemmArgs g{};
  g.Ab = cpostB; g.Bt = tranT; g.outB = U;
  g.M = 1024; g.N = 1024; g.K = 1024; g.lda = 1024; g.ldbt = 1024; g.ldc = 1024;
  k_gemm<64, 64, 2, 1, 0, EPI_BF16><<<dim3(16, 16), 128, 0, s>>>(g);
}

static void launch_g2cost(const unsigned short* U, const unsigned short* cpriorB,
                          const float* f1, const float* f2, const float* cpp,
                          float* cost, unsigned* mx, hipStream_t s)
{
  GemmArgs g{};
  g.Ab = U; g.Bt = cpriorB; g.outF = cost;
  g.f1 = f1; g.f2 = f2; g.cpp = cpp; g.mx = mx;
  g.M = 1024; g.N = 1024; g.K = 1024; g.lda = 1024; g.ldbt = 1024; g.ldc = 1024;
  k_gemm<64, 64, 2, 1, 0, EPI_COST><<<dim3(16, 16), 128, 0, s>>>(g);
}

static void launch_g2loss(const unsigned short* U, const unsigned short* cpriorB,
                          const float* f1, const float* f2, const float* cpp,
                          const float* tran, float* loss, hipStream_t s)
{
  GemmArgs g{};
  g.Ab = U; g.Bt = cpriorB;
  g.f1 = f1; g.f2 = f2; g.cpp = cpp; g.tranF = tran; g.loss = loss;
  g.M = 1024; g.N = 1024; g.K = 1024; g.lda = 1024; g.ldbt = 1024; g.ldc = 1024;
  k_gemm<64, 64, 2, 1, 0, EPI_LOSS><<<dim3(16, 16), 128, 0, s>>>(g);
}

// ---------------------------------------------------------------------------
extern "C" void kernel_launch(void* const* d_in, const int* in_sizes, int n_in,
                              void* d_out, int out_size, void* d_ws, size_t ws_size,
                              hipStream_t stream)
{
  (void)in_sizes; (void)n_in; (void)out_size; (void)ws_size;

  const float* X     = (const float*)d_in[2];
  const float* Y     = (const float*)d_in[3];
  const float* pmua  = (const float*)d_in[4];
  const float* plva  = (const float*)d_in[5];
  const float* pmub  = (const float*)d_in[6];
  const float* plvb  = (const float*)d_in[7];
  const float* epsx  = (const float*)d_in[8];
  const float* epsy  = (const float*)d_in[9];
  const float* epsxr = (const float*)d_in[10];
  const float* epsyr = (const float*)d_in[11];
  const float* W1a = (const float*)d_in[12];  const float* b1a = (const float*)d_in[13];
  const float* W21a= (const float*)d_in[14];  const float* b21a= (const float*)d_in[15];
  const float* W22a= (const float*)d_in[16];  const float* b22a= (const float*)d_in[17];
  const float* W3a = (const float*)d_in[18];  const float* b3a = (const float*)d_in[19];
  const float* W4a = (const float*)d_in[20];  const float* b4a = (const float*)d_in[21];
  const float* W1b = (const float*)d_in[22];  const float* b1b = (const float*)d_in[23];
  const float* W21b= (const float*)d_in[24];  const float* b21b= (const float*)d_in[25];
  const float* W22b= (const float*)d_in[26];  const float* b22b= (const float*)d_in[27];
  const float* W3b = (const float*)d_in[28];  const float* b3b = (const float*)d_in[29];
  const float* W4b = (const float*)d_in[30];  const float* b4b = (const float*)d_in[31];

  float* out = (float*)d_out;
  const size_t P_X = 0, P_Y = 20480000, P_X2Y = 46080000, P_Y2X = 71680000;
  const size_t Z_X = 92160000, Z_Y = 92225536;
  const size_t GMM_A = 92291072, GMM_B = 92291073;
  const size_t F_XR = 92291074, F_YR = 92356610;
  const size_t ALIGN = 92422146, CYC_X = 92422147, CYC_Y = 92422148;

  // ---- workspace carve (~84 MB)
  char* w = (char*)d_ws;
  size_t off = 0;
  auto alloc = [&](size_t bytes) -> void* {
    void* p = w + off;
    off += (bytes + 255) & ~(size_t)255;
    return p;
  };
  unsigned short* Wt1a = (unsigned short*)alloc((size_t)256 * 20000 * 2);
  unsigned short* Wt1b = (unsigned short*)alloc((size_t)256 * 25000 * 2);
  unsigned short* W4ta = (unsigned short*)alloc((size_t)20000 * 256 * 2);
  unsigned short* W4tb = (unsigned short*)alloc((size_t)25000 * 256 * 2);
  float* h    = (float*)alloc((size_t)1024 * 256 * 4);
  float* hdec = (float*)alloc((size_t)1024 * 256 * 4);
  float* mu_a = (float*)alloc(1024 * 64 * 4);
  float* lv_a = (float*)alloc(1024 * 64 * 4);
  float* mu_b = (float*)alloc(1024 * 64 * 4);
  float* lv_b = (float*)alloc(1024 * 64 * 4);
  float* mu_t = (float*)alloc(1024 * 64 * 4);
  float* lv_t = (float*)alloc(1024 * 64 * 4);
  float* f1   = (float*)alloc(1024 * 4);
  float* f2   = (float*)alloc(1024 * 4);
  unsigned* mx      = (unsigned*)alloc(16 * 4);
  unsigned* nanflag = (unsigned*)alloc(256);
  float* cyc  = (float*)alloc(256);
  float* dual = (float*)alloc(1024 * 4);
  float* bvec = (float*)alloc(1024 * 4);
  // arena: split-K partials (32 MB) aliased over FGW matrices (28 MB) — disjoint in time
  char* arena = (char*)alloc((size_t)34 * 1024 * 1024);
  float* partials = (float*)arena;
  size_t ao = 0;
  auto aalloc = [&](size_t bytes) -> void* {
    void* p = arena + ao;
    ao += (bytes + 255) & ~(size_t)255;
    return p;
  };
  unsigned short* cpostB  = (unsigned short*)aalloc((size_t)1024 * 1024 * 2);
  unsigned short* cpriorB = (unsigned short*)aalloc((size_t)1024 * 1024 * 2);
  float* cpp  = (float*)aalloc((size_t)1024 * 1024 * 4);
  float* tran = (float*)aalloc((size_t)1024 * 1024 * 4);
  unsigned short* tranT = (unsigned short*)aalloc((size_t)1024 * 1024 * 2);
  unsigned short* Umat  = (unsigned short*)aalloc((size_t)1024 * 1024 * 2);
  float* cost  = (float*)aalloc((size_t)1024 * 1024 * 4);
  float* Kmat  = (float*)aalloc((size_t)1024 * 1024 * 4);
  float* KTmat = (float*)aalloc((size_t)1024 * 1024 * 4);

  // ---- 1. weight prep (bf16 transposes)
  k_transpose<<<dim3(313, 4), 256, 0, stream>>>(W1a, Wt1a, 20000, 256);
  k_transpose<<<dim3(391, 4), 256, 0, stream>>>(W1b, Wt1b, 25000, 256);
  k_transpose<<<dim3(4, 313), 256, 0, stream>>>(W4a, W4ta, 256, 20000);
  k_transpose<<<dim3(4, 391), 256, 0, stream>>>(W4b, W4tb, 256, 25000);

  // ---- 2. init scalars / tran / dual
  k_init_small<<<1, 1024, 0, stream>>>(f1, f2, mx, nanflag, cyc,
                                       out + GMM_A, out + GMM_B, out + ALIGN);
  k_tran_init<<<4096, 256, 0, stream>>>(tran, tranT, dual);

  // ---- 3. encoders
  launch_enc(X, 20000, Wt1a, 20000, partials, stream);
  k_reduce_relu<<<1024, 256, 0, stream>>>(partials, b1a, h, 32);
  k_enc_head<<<1024, 128, 0, stream>>>(h, W21a, b21a, W22a, b22a, epsx, mu_a, lv_a, out + Z_X);

  launch_enc(Y, 25000, Wt1b, 25000, partials, stream);
  k_reduce_relu<<<1024, 256, 0, stream>>>(partials, b1b, h, 32);
  k_enc_head<<<1024, 128, 0, stream>>>(h, W21b, b21b, W22b, b22b, epsy, mu_b, lv_b, out + Z_Y);

  // ---- 4. FGW(mu_b, mu_a, lv_b, lv_a)
  k_dist<1, 1><<<dim3(16, 16), 256, 0, stream>>>(mu_b, lv_b, mu_b, lv_b, cpostB, nullptr, f1);
  k_dist<1, 1><<<dim3(16, 16), 256, 0, stream>>>(mu_a, lv_a, mu_a, lv_a, cpriorB, nullptr, f2);
  k_dist<0, 0><<<dim3(16, 16), 256, 0, stream>>>(mu_b, lv_b, mu_a, lv_a, nullptr, cpp, nullptr);
  for (int it = 0; it < 10; ++it) {
    launch_g1(cpostB, tranT, Umat, stream);
    launch_g2cost(Umat, cpriorB, f1, f2, cpp, cost, mx + it, stream);
    k_kbuild<<<dim3(16, 16), 256, 0, stream>>>(cost, tran, mx + it, Kmat, KTmat);
    k_matvec<<<256, 256, 0, stream>>>(KTmat, dual, bvec, 1.f / 1024.f);
    for (int r = 0; r < 5; ++r) {
      k_matvec<<<256, 256, 0, stream>>>(Kmat, bvec, dual, 1.f / 1024.f);
      k_matvec<<<256, 256, 0, stream>>>(KTmat, dual, bvec, 1.f / 1024.f);
    }
    k_tranupd<<<dim3(16, 16), 256, 0, stream>>>(Kmat, dual, bvec, tran, tranT);
  }
  k_nancheck<<<4096, 256, 0, stream>>>(tran, nanflag);
  k_nanfix<<<4096, 256, 0, stream>>>(tran, tranT, nanflag);
  launch_g1(cpostB, tranT, Umat, stream);
  launch_g2loss(Umat, cpriorB, f1, f2, cpp, tran, out + ALIGN, stream);

  // ---- 5. decoders
  k_dec_head<<<1024, 256, 0, stream>>>(out + Z_X, W3a, b3a, hdec);
  launch_dec(hdec, W4ta, b4a, 20000, out + P_X, stream);
  k_dec_head<<<1024, 256, 0, stream>>>(out + Z_Y, W3b, b3b, hdec);
  launch_dec(hdec, W4tb, b4b, 25000, out + P_Y, stream);
  k_dec_head<<<1024, 256, 0, stream>>>(out + Z_X, W3b, b3b, hdec);
  launch_dec(hdec, W4tb, b4b, 25000, out + P_X2Y, stream);
  k_dec_head<<<1024, 256, 0, stream>>>(out + Z_Y, W3a, b3a, hdec);
  launch_dec(hdec, W4ta, b4a, 20000, out + P_Y2X, stream);

  // ---- 6. re-encode cross predictions
  launch_enc(out + P_X2Y, 25000, Wt1b, 25000, partials, stream);
  k_reduce_relu<<<1024, 256, 0, stream>>>(partials, b1b, h, 32);
  k_enc_head<<<1024, 128, 0, stream>>>(h, W21b, b21b, W22b, b22b, epsxr, mu_t, lv_t, out + F_XR);

  launch_enc(out + P_Y2X, 20000, Wt1a, 20000, partials, stream);
  k_reduce_relu<<<1024, 256, 0, stream>>>(partials, b1a, h, 32);
  k_enc_head<<<1024, 128, 0, stream>>>(h, W21a, b21a, W22a, b22a, epsyr, mu_t, lv_t, out + F_YR);

  // ---- 7. GMM losses
  k_gmm<<<1024, 64, 0, stream>>>(out + Z_X, mu_a, lv_a, pmua, plva, out + GMM_A);
  k_gmm<<<1024, 64, 0, stream>>>(out + Z_Y, mu_b, lv_b, pmub, plvb, out + GMM_B);

  // ---- 8. cycle losses
  k_sqdiff<<<256, 256, 0, stream>>>(out + Z_X, out + F_XR, cyc + 0);
  k_sqdiff<<<256, 256, 0, stream>>>(out + Z_Y, out + F_YR, cyc + 1);
  k_finish<<<1, 64, 0, stream>>>(cyc, out + CYC_X, out + CYC_Y);
}

// Round 3
// 2243.366 us; speedup vs baseline: 1.2410x; 1.2410x over previous
//
#include <hip/hip_runtime.h>

// ============================================================================
// MUCRP_17265768530653 — cross-domain VAE forward on MI355X (gfx950)
// Round 3: round-1 structure (passed), with FGW 1024^3 GEMMs upgraded from
// 2-wave to 4-wave (2x2) blocks, and the NaN-check fused into tranupd.
// Cooperative grid.sync was abandoned: it produced replay-only NaNs (XCD
// visibility under graph replay) and was slower.
// ============================================================================

#define DEVI __device__ __forceinline__

typedef __attribute__((ext_vector_type(4))) float  f32x4;
typedef __attribute__((ext_vector_type(4))) short  s16x4;
typedef __attribute__((ext_vector_type(8))) short  s16x8;
typedef __attribute__((ext_vector_type(8))) __bf16 bf16x8;

DEVI short f2bf(float f) {              // RNE f32 -> bf16 (bits)
  unsigned u = __float_as_uint(f);
  u += 0x7fffu + ((u >> 16) & 1u);
  return (short)(u >> 16);
}

DEVI f32x4 mfma16(bf16x8 a, bf16x8 b, f32x4 c) {
  return __builtin_amdgcn_mfma_f32_16x16x32_bf16(a, b, c, 0, 0, 0);
}

// ---------------------------------------------------------------------------
// Generic tiled MFMA GEMM for encoder/decoder passes.
// A: f32 row-major [M][lda].  B: bf16 TRANSPOSED [N][ldbt] (k fast).
// ---------------------------------------------------------------------------
struct GemmArgs {
  const float* Af;
  const unsigned short* Bt;
  float* outF;
  const float* bias;
  float* partials;
  int M, N, K;
  int lda, ldbt, ldc;
  int totSteps, nSplits;
};

enum { EPI_PARTIAL, EPI_BIAS, EPI_BF16, EPI_COST, EPI_LOSS };

template<int BM, int BN, int WR, int WC, int EPI>
__global__ __launch_bounds__(WR*WC*64)
void k_gemm(GemmArgs g)
{
  constexpr int BK = 64, BKP = 72;
  constexpr int NT = WR * WC * 64;
  __shared__ short As[BM * BKP];
  __shared__ short Bs[BN * BKP];

  const int m0 = blockIdx.x * BM;
  int n0 = 0, kb0 = 0, kb1 = g.K, split = 0;
  if constexpr (EPI == EPI_PARTIAL) {
    split = blockIdx.y;
    int s0 = (split * g.totSteps) / g.nSplits;
    int s1 = ((split + 1) * g.totSteps) / g.nSplits;
    kb0 = s0 * BK;
    kb1 = s1 * BK; if (kb1 > g.K) kb1 = g.K;
  } else {
    n0 = blockIdx.y * BN;
  }
  const int tid  = threadIdx.x;
  const int lane = tid & 63;
  const int wv   = tid >> 6;
  const int wr   = wv % WR;
  const int wc   = wv / WR;

  f32x4 acc[2][4];
  #pragma unroll
  for (int i = 0; i < 2; ++i)
    #pragma unroll
    for (int j = 0; j < 4; ++j) acc[i][j] = f32x4{0.f, 0.f, 0.f, 0.f};

  for (int kb = kb0; kb < kb1; kb += BK) {
    {   // stage A (f32 -> bf16)
      constexpr int NV = BM * BK / 4;
      #pragma unroll
      for (int i = 0; i < NV / NT; ++i) {
        int idx = tid + NT * i;
        int r = idx >> 4, q = idx & 15;
        int k = kb + 4 * q;
        f32x4 v = f32x4{0.f, 0.f, 0.f, 0.f};
        if (k < kb1) v = *(const f32x4*)(g.Af + (size_t)(m0 + r) * g.lda + k);
        s16x4 s;
        s.x = f2bf(v.x); s.y = f2bf(v.y); s.z = f2bf(v.z); s.w = f2bf(v.w);
        *(s16x4*)&As[r * BKP + 4 * q] = s;
      }
    }
    {   // stage B (bf16 [N][K])
      constexpr int NV = BN * BK / 8;
      #pragma unroll
      for (int i = 0; i < NV / NT; ++i) {
        int idx = tid + NT * i;
        int r = idx >> 3, q = idx & 7;
        int k = kb + 8 * q;
        s16x8 v{};
        if ((n0 + r) < g.N && k < kb1)
          v = *(const s16x8*)(g.Bt + (size_t)(n0 + r) * g.ldbt + k);
        *(s16x8*)&Bs[r * BKP + 8 * q] = v;
      }
    }
    __syncthreads();
    #pragma unroll
    for (int s = 0; s < 2; ++s) {
      const int ko = 32 * s + 8 * (lane >> 4);
      bf16x8 a0 = *(const bf16x8*)&As[(wr * 32 +      (lane & 15)) * BKP + ko];
      bf16x8 a1 = *(const bf16x8*)&As[(wr * 32 + 16 + (lane & 15)) * BKP + ko];
      #pragma unroll
      for (int fn = 0; fn < 4; ++fn) {
        bf16x8 b = *(const bf16x8*)&Bs[(wc * 64 + fn * 16 + (lane & 15)) * BKP + ko];
        acc[0][fn] = mfma16(a0, b, acc[0][fn]);
        acc[1][fn] = mfma16(a1, b, acc[1][fn]);
      }
    }
    __syncthreads();
  }

  #pragma unroll
  for (int fm = 0; fm < 2; ++fm) {
    #pragma unroll
    for (int fn = 0; fn < 4; ++fn) {
      #pragma unroll
      for (int p = 0; p < 4; ++p) {
        int gm = m0 + wr * 32 + fm * 16 + (lane >> 4) * 4 + p;
        int gn = n0 + wc * 64 + fn * 16 + (lane & 15);
        float v = acc[fm][fn][p];
        if constexpr (EPI == EPI_PARTIAL) {
          g.partials[((size_t)split * g.M + gm) * 256 + gn] = v;
        } else {
          if (gn < g.N) g.outF[(size_t)gm * g.ldc + gn] = v + g.bias[gn];
        }
      }
    }
  }
}

// ---------------------------------------------------------------------------
// FGW 1024^3 GEMM, 4-wave (2x2) 64x64 tile, 256 blocks.  A bf16 [1024][1024]
// row-major (k fast); Bt bf16 [1024][1024] (n-major, k fast).
// ---------------------------------------------------------------------------
struct FgwGemmArgs {
  const unsigned short* A;
  const unsigned short* Bt;
  unsigned short* U;        // EPI_BF16 out
  float* cost;              // EPI_COST out
  const float* f1;
  const float* f2;
  const float* cpp;
  const float* tran;        // EPI_LOSS in
  unsigned* mx;
  float* loss;
};

template<int EPI>
__global__ __launch_bounds__(256)
void k_fgw_gemm(FgwGemmArgs a)
{
  __shared__ short As[64 * 72];
  __shared__ short Bs[64 * 72];
  __shared__ float red[4];

  const int bid = blockIdx.x, tid = threadIdx.x;
  const int lane = tid & 63, wv = tid >> 6;
  const int wr = wv & 1, wc = wv >> 1;          // 2x2 waves, 32x32 each
  const int m0 = (bid >> 4) * 64, n0 = (bid & 15) * 64;

  f32x4 acc[2][2];
  #pragma unroll
  for (int i = 0; i < 2; ++i)
    #pragma unroll
    for (int j = 0; j < 2; ++j) acc[i][j] = f32x4{0.f, 0.f, 0.f, 0.f};

  for (int kb = 0; kb < 1024; kb += 64) {
    #pragma unroll
    for (int i = 0; i < 2; ++i) {
      int idx = tid + 256 * i;
      int r = idx >> 3, q = idx & 7;
      *(s16x8*)&As[r * 72 + 8 * q] = *(const s16x8*)&a.A [(size_t)(m0 + r) * 1024 + kb + 8 * q];
      *(s16x8*)&Bs[r * 72 + 8 * q] = *(const s16x8*)&a.Bt[(size_t)(n0 + r) * 1024 + kb + 8 * q];
    }
    __syncthreads();
    #pragma unroll
    for (int s = 0; s < 2; ++s) {
      const int ko = 32 * s + 8 * (lane >> 4);
      bf16x8 a0 = *(const bf16x8*)&As[(wr * 32 +      (lane & 15)) * 72 + ko];
      bf16x8 a1 = *(const bf16x8*)&As[(wr * 32 + 16 + (lane & 15)) * 72 + ko];
      bf16x8 b0 = *(const bf16x8*)&Bs[(wc * 32 +      (lane & 15)) * 72 + ko];
      bf16x8 b1 = *(const bf16x8*)&Bs[(wc * 32 + 16 + (lane & 15)) * 72 + ko];
      acc[0][0] = mfma16(a0, b0, acc[0][0]);
      acc[1][0] = mfma16(a1, b0, acc[1][0]);
      acc[0][1] = mfma16(a0, b1, acc[0][1]);
      acc[1][1] = mfma16(a1, b1, acc[1][1]);
    }
    __syncthreads();
  }

  float lred = 0.f;
  #pragma unroll
  for (int fm = 0; fm < 2; ++fm) {
    #pragma unroll
    for (int fn = 0; fn < 2; ++fn) {
      #pragma unroll
      for (int p = 0; p < 4; ++p) {
        int gm = m0 + wr * 32 + fm * 16 + (lane >> 4) * 4 + p;
        int gn = n0 + wc * 32 + fn * 16 + (lane & 15);
        float v = acc[fm][fn][p];
        size_t o = (size_t)gm * 1024 + gn;
        if constexpr (EPI == EPI_BF16) {
          a.U[o] = (unsigned short)f2bf(v);
        } else {
          float c = 0.1f * (a.f1[gm] + a.f2[gn] - 2.f * v) + 0.9f * a.cpp[o];
          if constexpr (EPI == EPI_COST) {
            a.cost[o] = c;
            lred = fmaxf(lred, fabsf(c));
          } else {
            lred += c * a.tran[o];
          }
        }
      }
    }
  }
  if constexpr (EPI != EPI_BF16) {
    #pragma unroll
    for (int off = 32; off; off >>= 1) {
      float t = __shfl_xor(lred, off, 64);
      lred = (EPI == EPI_COST) ? fmaxf(lred, t) : (lred + t);
    }
    if (lane == 0) red[wv] = lred;
    __syncthreads();
    if (tid == 0) {
      if constexpr (EPI == EPI_COST) {
        float t = fmaxf(fmaxf(red[0], red[1]), fmaxf(red[2], red[3]));
        atomicMax(a.mx, __float_as_uint(t));
      } else {
        atomicAdd(a.loss, red[0] + red[1] + red[2] + red[3]);
      }
    }
  }
}

// ---------------------------------------------------------------------------
// f32 [R][C] -> bf16 [C][R] tiled transpose (weight prep)
// ---------------------------------------------------------------------------
__global__ void k_transpose(const float* in, unsigned short* out, int R, int C)
{
  __shared__ float t[64][65];
  const int r0 = blockIdx.x * 64, c0 = blockIdx.y * 64;
  const int tid = threadIdx.x;
  #pragma unroll
  for (int i = 0; i < 16; ++i) {
    int idx = tid + 256 * i;
    int r = idx >> 6, c = idx & 63;
    float v = 0.f;
    if ((r0 + r) < R && (c0 + c) < C) v = in[(size_t)(r0 + r) * C + (c0 + c)];
    t[r][c] = v;
  }
  __syncthreads();
  #pragma unroll
  for (int i = 0; i < 16; ++i) {
    int idx = tid + 256 * i;
    int c = idx >> 6, r = idx & 63;
    if ((c0 + c) < C && (r0 + r) < R)
      out[(size_t)(c0 + c) * R + (r0 + r)] = (unsigned short)f2bf(t[r][c]);
  }
}

__global__ void k_reduce_relu(const float* partials, const float* bias, float* h, int ns)
{
  int idx = blockIdx.x * 256 + threadIdx.x;
  float s = bias[idx & 255];
  for (int p = 0; p < ns; ++p) s += partials[(size_t)p * (1024 * 256) + idx];
  h[idx] = fmaxf(s, 0.f);
}

__global__ void k_enc_head(const float* h, const float* W21, const float* b21,
                           const float* W22, const float* b22, const float* eps,
                           float* muO, float* lvO, float* zO)
{
  __shared__ float hrow[256];
  __shared__ float res[128];
  const int i = blockIdx.x;
  const int t = threadIdx.x;                  // 128
  hrow[t]       = h[(size_t)i * 256 + t];
  hrow[t + 128] = h[(size_t)i * 256 + t + 128];
  __syncthreads();
  const int c = t & 63;
  const float* W = (t < 64) ? W21 : W22;
  float a = (t < 64) ? b21[c] : b22[c];
  #pragma unroll 8
  for (int j = 0; j < 256; ++j) a += hrow[j] * W[j * 64 + c];
  res[t] = a;
  __syncthreads();
  if (t < 64) {
    float mu = res[t], lv = res[64 + t];
    muO[(size_t)i * 64 + t] = mu;
    lvO[(size_t)i * 64 + t] = lv;
    zO[(size_t)i * 64 + t]  = mu + eps[(size_t)i * 64 + t] * expf(0.5f * lv);
  }
}

__global__ void k_dec_head(const float* z, const float* W3, const float* b3, float* hd)
{
  __shared__ float zrow[64];
  const int i = blockIdx.x;
  const int t = threadIdx.x;                  // 256
  if (t < 64) zrow[t] = z[(size_t)i * 64 + t];
  __syncthreads();
  float a = b3[t];
  #pragma unroll
  for (int d = 0; d < 64; ++d) a += zrow[d] * W3[d * 256 + t];
  hd[(size_t)i * 256 + t] = fmaxf(a, 0.f);
}

// ---------------------------------------------------------------------------
// _distance_gmm 64x64 tile
// ---------------------------------------------------------------------------
template<int WRITE_BF, int DO_F>
__global__ void k_dist(const float* xmu, const float* xlv, const float* ymu, const float* ylv,
                       unsigned short* outB, float* outF, float* frow)
{
  __shared__ float SX[64 * 68];
  __shared__ float SY[64 * 68];
  const int r0 = blockIdx.x * 64, c0 = blockIdx.y * 64;
  const int t = threadIdx.x;                  // 256
  const int rr = t >> 2;
  const int c4 = (t & 3) * 16;
  float acc[16];
  #pragma unroll
  for (int i = 0; i < 16; ++i) acc[i] = 0.f;

  for (int pass = 0; pass < 2; ++pass) {
    __syncthreads();
    #pragma unroll
    for (int i = 0; i < 16; ++i) {
      int idx = t + 256 * i;
      int r = idx >> 6, d = idx & 63;
      float vx, vy;
      if (pass == 0) {
        vx = xmu[(size_t)(r0 + r) * 64 + d];
        vy = ymu[(size_t)(c0 + r) * 64 + d];
      } else {
        vx = expf(0.5f * xlv[(size_t)(r0 + r) * 64 + d]);
        vy = expf(0.5f * ylv[(size_t)(c0 + r) * 64 + d]);
      }
      SX[r * 68 + d] = vx;
      SY[r * 68 + d] = vy;
    }
    __syncthreads();
    #pragma unroll
    for (int i = 0; i < 16; ++i) {
      int cc = c4 + i;
      float s = 0.f;
      #pragma unroll
      for (int d4 = 0; d4 < 16; ++d4) {
        f32x4 a = *(const f32x4*)&SX[rr * 68 + 4 * d4];
        f32x4 b = *(const f32x4*)&SY[cc * 68 + 4 * d4];
        f32x4 df = a - b;
        s += df.x * df.x + df.y * df.y + df.z * df.z + df.w * df.w;
      }
      acc[i] += s;
    }
  }
  float fpart = 0.f;
  #pragma unroll
  for (int i = 0; i < 16; ++i) {
    int cc = c4 + i;
    float val = acc[i] + 1e-6f;
    if constexpr (WRITE_BF) outB[(size_t)(r0 + rr) * 1024 + (c0 + cc)] = (unsigned short)f2bf(val);
    else                    outF[(size_t)(r0 + rr) * 1024 + (c0 + cc)] = val;
    if constexpr (DO_F) fpart += val * val;
  }
  if constexpr (DO_F) {
    fpart += __shfl_xor(fpart, 1, 64);
    fpart += __shfl_xor(fpart, 2, 64);
    if ((t & 3) == 0) atomicAdd(frow + (r0 + rr), fpart * (1.f / 1024.f));
  }
}

// K = exp(-cost/mx) * tran ; also write K^T (tiled)
__global__ void k_kbuild(const float* cost, const float* tran, const unsigned* mxbits,
                         float* K, float* KT)
{
  __shared__ float t[64][65];
  const int r0 = blockIdx.x * 64, c0 = blockIdx.y * 64;
  const int tid = threadIdx.x;
  const float inv = 1.f / __uint_as_float(*mxbits);
  #pragma unroll
  for (int i = 0; i < 16; ++i) {
    int idx = tid + 256 * i;
    int r = idx >> 6, c = idx & 63;
    size_t o = (size_t)(r0 + r) * 1024 + (c0 + c);
    float v = expf(-cost[o] * inv) * tran[o];
    K[o] = v;
    t[r][c] = v;
  }
  __syncthreads();
  #pragma unroll
  for (int i = 0; i < 16; ++i) {
    int idx = tid + 256 * i;
    int c = idx >> 6, r = idx & 63;
    KT[(size_t)(c0 + c) * 1024 + (r0 + r)] = t[r][c];
  }
}

// y_i = p / (M[i,:] . x).  4 rows per block (one per wave).
__global__ void k_matvec(const float* M, const float* x, float* y, float pval)
{
  const int r = blockIdx.x * 4 + (threadIdx.x >> 6);
  const int lane = threadIdx.x & 63;
  const f32x4* row = (const f32x4*)(M + (size_t)r * 1024);
  const f32x4* xv  = (const f32x4*)x;
  float s = 0.f;
  #pragma unroll
  for (int q = 0; q < 4; ++q) {
    f32x4 a = row[lane + 64 * q];
    f32x4 b = xv [lane + 64 * q];
    s += a.x * b.x + a.y * b.y + a.z * b.z + a.w * b.w;
  }
  #pragma unroll
  for (int o = 32; o; o >>= 1) s += __shfl_xor(s, o, 64);
  if (lane == 0) y[r] = pval / s;
}

// tran = (dual (x) b) * K ; emit tran^T bf16; optional NaN-flag (last iter)
__global__ void k_tranupd(const float* K, const float* dual, const float* bv,
                          float* tran, unsigned short* tranT, unsigned* flag, int check)
{
  __shared__ float t[64][65];
  const int r0 = blockIdx.x * 64, c0 = blockIdx.y * 64;
  const int tid = threadIdx.x;
  unsigned bad = 0;
  #pragma unroll
  for (int i = 0; i < 16; ++i) {
    int idx = tid + 256 * i;
    int r = idx >> 6, c = idx & 63;
    size_t o = (size_t)(r0 + r) * 1024 + (c0 + c);
    float v = dual[r0 + r] * bv[c0 + c] * K[o];
    tran[o] = v;
    t[r][c] = v;
    if (v != v) bad = 1u;
  }
  __syncthreads();
  #pragma unroll
  for (int i = 0; i < 16; ++i) {
    int idx = tid + 256 * i;
    int c = idx >> 6, r = idx & 63;
    tranT[(size_t)(c0 + c) * 1024 + (r0 + r)] = (unsigned short)f2bf(t[r][c]);
  }
  if (check && bad) atomicOr(flag, 1u);
}

__global__ void k_init_small(float* f1, float* f2, unsigned* mx, unsigned* nanflag,
                             float* cyc, float* ga, float* gb, float* al, float* dual)
{
  int t = threadIdx.x;                        // 1024
  f1[t] = 0.f; f2[t] = 0.f;
  dual[t] = 1.f / 1024.f;
  if (t < 16) mx[t] = 0u;
  if (t == 0) { *nanflag = 0u; cyc[0] = 0.f; cyc[1] = 0.f; *ga = 0.f; *gb = 0.f; *al = 0.f; }
}

__global__ void k_tran_init(float* tran, unsigned short* tranT)
{
  int idx = blockIdx.x * 256 + threadIdx.x;
  const float v = 1.f / (1024.f * 1024.f);
  tran[idx]  = v;
  tranT[idx] = (unsigned short)f2bf(v);
}

__global__ void k_nanfix(float* tran, unsigned short* tranT, const unsigned* flag)
{
  if (*flag == 0u) return;
  int idx = blockIdx.x * 256 + threadIdx.x;
  const float v = 1.f / (1024.f * 1024.f);
  tran[idx]  = v;
  tranT[idx] = (unsigned short)f2bf(v);
}

// GMM KL row contribution; one wave per batch row, atomicAdd into scalar.
__global__ void k_gmm(const float* z, const float* mu, const float* lv,
                      const float* pmu, const float* plv, float* outsc)
{
  const int i = blockIdx.x;
  const int d = threadIdx.x;                  // 64
  const float zd = z[(size_t)i * 64 + d];
  const float m  = mu[(size_t)i * 64 + d];
  const float l  = lv[(size_t)i * 64 + d];
  float t = l + (zd - m) * (zd - m) * expf(-l);
  #pragma unroll
  for (int o = 32; o; o >>= 1) t += __shfl_xor(t, o, 64);
  const float C0 = 64.f * 1.8378770664093453f;
  float logq = -0.5f * (C0 + t);
  float lp[20];
  #pragma unroll
  for (int k = 0; k < 20; ++k) {
    float pm = pmu[k * 64 + d], pl = plv[k * 64 + d];
    float u = pl + (zd - pm) * (zd - pm) * expf(-pl);
    #pragma unroll
    for (int o = 32; o; o >>= 1) u += __shfl_xor(u, o, 64);
    lp[k] = -0.5f * (C0 + u);
  }
  float mx = lp[0];
  #pragma unroll
  for (int k = 1; k < 20; ++k) mx = fmaxf(mx, lp[k]);
  float s = 0.f;
  #pragma unroll
  for (int k = 0; k < 20; ++k) s += expf(lp[k] - mx);
  float logp = mx + logf(s) - 2.9957322735539909f;
  if (d == 0) atomicAdd(outsc, logq - logp);
}

__global__ void k_sqdiff(const float* a, const float* b, float* slot)
{
  __shared__ float red[4];
  int idx = blockIdx.x * 256 + threadIdx.x;
  float d = a[idx] - b[idx];
  d = d * d;
  #pragma unroll
  for (int o = 32; o; o >>= 1) d += __shfl_xor(d, o, 64);
  int lane = threadIdx.x & 63, wv = threadIdx.x >> 6;
  if (lane == 0) red[wv] = d;
  __syncthreads();
  if (threadIdx.x == 0) atomicAdd(slot, red[0] + red[1] + red[2] + red[3]);
}

__global__ void k_finish(const float* slots, float* o1, float* o2)
{
  if (threadIdx.x == 0) { *o1 = sqrtf(slots[0]); *o2 = sqrtf(slots[1]); }
}

// ---------------------------------------------------------------------------
// launch helpers
// ---------------------------------------------------------------------------
static void launch_enc(const float* A, int lda, const unsigned short* Bt, int Kdim,
                       float* partials, hipStream_t s)
{
  GemmArgs g{};
  g.Af = A; g.Bt = Bt; g.partials = partials;
  g.M = 1024; g.N = 256; g.K = Kdim; g.lda = lda; g.ldbt = Kdim;
  g.totSteps = (Kdim + 63) / 64; g.nSplits = 32;
  k_gemm<128, 256, 4, 4, EPI_PARTIAL><<<dim3(8, 32), 1024, 0, s>>>(g);
}

static void launch_dec(const float* hd, const unsigned short* W4t, const float* bias,
                       int N, float* outp, hipStream_t s)
{
  GemmArgs g{};
  g.Af = hd; g.Bt = W4t; g.outF = outp; g.bias = bias;
  g.M = 1024; g.N = N; g.K = 256; g.lda = 256; g.ldbt = 256; g.ldc = N;
  k_gemm<128, 256, 4, 4, EPI_BIAS><<<dim3(8, (N + 255) / 256), 1024, 0, s>>>(g);
}

// ---------------------------------------------------------------------------
extern "C" void kernel_launch(void* const* d_in, const int* in_sizes, int n_in,
                              void* d_out, int out_size, void* d_ws, size_t ws_size,
                              hipStream_t stream)
{
  (void)in_sizes; (void)n_in; (void)out_size; (void)ws_size;

  const float* X     = (const float*)d_in[2];
  const float* Y     = (const float*)d_in[3];
  const float* pmua  = (const float*)d_in[4];
  const float* plva  = (const float*)d_in[5];
  const float* pmub  = (const float*)d_in[6];
  const float* plvb  = (const float*)d_in[7];
  const float* epsx  = (const float*)d_in[8];
  const float* epsy  = (const float*)d_in[9];
  const float* epsxr = (const float*)d_in[10];
  const float* epsyr = (const float*)d_in[11];
  const float* W1a = (const float*)d_in[12];  const float* b1a = (const float*)d_in[13];
  const float* W21a= (const float*)d_in[14];  const float* b21a= (const float*)d_in[15];
  const float* W22a= (const float*)d_in[16];  const float* b22a= (const float*)d_in[17];
  const float* W3a = (const float*)d_in[18];  const float* b3a = (const float*)d_in[19];
  const float* W4a = (const float*)d_in[20];  const float* b4a = (const float*)d_in[21];
  const float* W1b = (const float*)d_in[22];  const float* b1b = (const float*)d_in[23];
  const float* W21b= (const float*)d_in[24];  const float* b21b= (const float*)d_in[25];
  const float* W22b= (const float*)d_in[26];  const float* b22b= (const float*)d_in[27];
  const float* W3b = (const float*)d_in[28];  const float* b3b = (const float*)d_in[29];
  const float* W4b = (const float*)d_in[30];  const float* b4b = (const float*)d_in[31];

  float* out = (float*)d_out;
  const size_t P_X = 0, P_Y = 20480000, P_X2Y = 46080000, P_Y2X = 71680000;
  const size_t Z_X = 92160000, Z_Y = 92225536;
  const size_t GMM_A = 92291072, GMM_B = 92291073;
  const size_t F_XR = 92291074, F_YR = 92356610;
  const size_t ALIGN = 92422146, CYC_X = 92422147, CYC_Y = 92422148;

  // ---- workspace carve
  char* w = (char*)d_ws;
  size_t off = 0;
  auto alloc = [&](size_t bytes) -> void* {
    void* p = w + off;
    off += (bytes + 255) & ~(size_t)255;
    return p;
  };
  unsigned short* Wt1a = (unsigned short*)alloc((size_t)256 * 20000 * 2);
  unsigned short* Wt1b = (unsigned short*)alloc((size_t)256 * 25000 * 2);
  unsigned short* W4ta = (unsigned short*)alloc((size_t)20000 * 256 * 2);
  unsigned short* W4tb = (unsigned short*)alloc((size_t)25000 * 256 * 2);
  float* h    = (float*)alloc((size_t)1024 * 256 * 4);
  float* hdec = (float*)alloc((size_t)1024 * 256 * 4);
  float* mu_a = (float*)alloc(1024 * 64 * 4);
  float* lv_a = (float*)alloc(1024 * 64 * 4);
  float* mu_b = (float*)alloc(1024 * 64 * 4);
  float* lv_b = (float*)alloc(1024 * 64 * 4);
  float* mu_t = (float*)alloc(1024 * 64 * 4);
  float* lv_t = (float*)alloc(1024 * 64 * 4);
  float* f1   = (float*)alloc(1024 * 4);
  float* f2   = (float*)alloc(1024 * 4);
  unsigned* mx      = (unsigned*)alloc(16 * 4);
  unsigned* nanflag = (unsigned*)alloc(256);
  float* cyc  = (float*)alloc(256);
  float* dual = (float*)alloc(1024 * 4);
  float* bvec = (float*)alloc(1024 * 4);
  // arena: split-K partials (32 MB) aliased over FGW matrices (disjoint in time)
  char* arena = (char*)alloc((size_t)34 * 1024 * 1024);
  float* partials = (float*)arena;
  size_t ao = 0;
  auto aalloc = [&](size_t bytes) -> void* {
    void* p = arena + ao;
    ao += (bytes + 255) & ~(size_t)255;
    return p;
  };
  unsigned short* cpostB  = (unsigned short*)aalloc((size_t)1024 * 1024 * 2);
  unsigned short* cpriorB = (unsigned short*)aalloc((size_t)1024 * 1024 * 2);
  float* cpp  = (float*)aalloc((size_t)1024 * 1024 * 4);
  float* tran = (float*)aalloc((size_t)1024 * 1024 * 4);
  unsigned short* tranT = (unsigned short*)aalloc((size_t)1024 * 1024 * 2);
  unsigned short* Umat  = (unsigned short*)aalloc((size_t)1024 * 1024 * 2);
  float* cost  = (float*)aalloc((size_t)1024 * 1024 * 4);
  float* Kmat  = (float*)aalloc((size_t)1024 * 1024 * 4);
  float* KTmat = (float*)aalloc((size_t)1024 * 1024 * 4);

  // ---- 1. weight prep
  k_transpose<<<dim3(313, 4), 256, 0, stream>>>(W1a, Wt1a, 20000, 256);
  k_transpose<<<dim3(391, 4), 256, 0, stream>>>(W1b, Wt1b, 25000, 256);
  k_transpose<<<dim3(4, 313), 256, 0, stream>>>(W4a, W4ta, 256, 20000);
  k_transpose<<<dim3(4, 391), 256, 0, stream>>>(W4b, W4tb, 256, 25000);

  // ---- 2. init scalars / tran / dual
  k_init_small<<<1, 1024, 0, stream>>>(f1, f2, mx, nanflag, cyc,
                                       out + GMM_A, out + GMM_B, out + ALIGN, dual);
  k_tran_init<<<4096, 256, 0, stream>>>(tran, tranT);

  // ---- 3. encoders
  launch_enc(X, 20000, Wt1a, 20000, partials, stream);
  k_reduce_relu<<<1024, 256, 0, stream>>>(partials, b1a, h, 32);
  k_enc_head<<<1024, 128, 0, stream>>>(h, W21a, b21a, W22a, b22a, epsx, mu_a, lv_a, out + Z_X);

  launch_enc(Y, 25000, Wt1b, 25000, partials, stream);
  k_reduce_relu<<<1024, 256, 0, stream>>>(partials, b1b, h, 32);
  k_enc_head<<<1024, 128, 0, stream>>>(h, W21b, b21b, W22b, b22b, epsy, mu_b, lv_b, out + Z_Y);

  // ---- 4. FGW(mu_b, mu_a, lv_b, lv_a)
  k_dist<1, 1><<<dim3(16, 16), 256, 0, stream>>>(mu_b, lv_b, mu_b, lv_b, cpostB, nullptr, f1);
  k_dist<1, 1><<<dim3(16, 16), 256, 0, stream>>>(mu_a, lv_a, mu_a, lv_a, cpriorB, nullptr, f2);
  k_dist<0, 0><<<dim3(16, 16), 256, 0, stream>>>(mu_b, lv_b, mu_a, lv_a, nullptr, cpp, nullptr);

  FgwGemmArgs fg{};
  fg.f1 = f1; fg.f2 = f2; fg.cpp = cpp; fg.loss = out + ALIGN;
  for (int it = 0; it < 10; ++it) {
    fg.A = cpostB; fg.Bt = tranT; fg.U = Umat;
    k_fgw_gemm<EPI_BF16><<<256, 256, 0, stream>>>(fg);
    fg.A = Umat; fg.Bt = cpriorB; fg.cost = cost; fg.mx = mx + it;
    k_fgw_gemm<EPI_COST><<<256, 256, 0, stream>>>(fg);
    k_kbuild<<<dim3(16, 16), 256, 0, stream>>>(cost, tran, mx + it, Kmat, KTmat);
    k_matvec<<<256, 256, 0, stream>>>(KTmat, dual, bvec, 1.f / 1024.f);
    for (int r = 0; r < 5; ++r) {
      k_matvec<<<256, 256, 0, stream>>>(Kmat, bvec, dual, 1.f / 1024.f);
      k_matvec<<<256, 256, 0, stream>>>(KTmat, dual, bvec, 1.f / 1024.f);
    }
    k_tranupd<<<dim3(16, 16), 256, 0, stream>>>(Kmat, dual, bvec, tran, tranT,
                                                nanflag, it == 9 ? 1 : 0);
  }
  k_nanfix<<<4096, 256, 0, stream>>>(tran, tranT, nanflag);
  fg.A = cpostB; fg.Bt = tranT; fg.U = Umat;
  k_fgw_gemm<EPI_BF16><<<256, 256, 0, stream>>>(fg);
  fg.A = Umat; fg.Bt = cpriorB; fg.tran = tran;
  k_fgw_gemm<EPI_LOSS><<<256, 256, 0, stream>>>(fg);

  // ---- 5. decoders
  k_dec_head<<<1024, 256, 0, stream>>>(out + Z_X, W3a, b3a, hdec);
  launch_dec(hdec, W4ta, b4a, 20000, out + P_X, stream);
  k_dec_head<<<1024, 256, 0, stream>>>(out + Z_Y, W3b, b3b, hdec);
  launch_dec(hdec, W4tb, b4b, 25000, out + P_Y, stream);
  k_dec_head<<<1024, 256, 0, stream>>>(out + Z_X, W3b, b3b, hdec);
  launch_dec(hdec, W4tb, b4b, 25000, out + P_X2Y, stream);
  k_dec_head<<<1024, 256, 0, stream>>>(out + Z_Y, W3a, b3a, hdec);
  launch_dec(hdec, W4ta, b4a, 20000, out + P_Y2X, stream);

  // ---- 6. re-encode cross predictions
  launch_enc(out + P_X2Y, 25000, Wt1b, 25000, partials, stream);
  k_reduce_relu<<<1024, 256, 0, stream>>>(partials, b1b, h, 32);
  k_enc_head<<<1024, 128, 0, stream>>>(h, W21b, b21b, W22b, b22b, epsxr, mu_t, lv_t, out + F_XR);

  launch_enc(out + P_Y2X, 20000, Wt1a, 20000, partials, stream);
  k_reduce_relu<<<1024, 256, 0, stream>>>(partials, b1a, h, 32);
  k_enc_head<<<1024, 128, 0, stream>>>(h, W21a, b21a, W22a, b22a, epsyr, mu_t, lv_t, out + F_YR);

  // ---- 7. GMM losses
  k_gmm<<<1024, 64, 0, stream>>>(out + Z_X, mu_a, lv_a, pmua, plva, out + GMM_A);
  k_gmm<<<1024, 64, 0, stream>>>(out + Z_Y, mu_b, lv_b, pmub, plvb, out + GMM_B);

  // ---- 8. cycle losses
  k_sqdiff<<<256, 256, 0, stream>>>(out + Z_X, out + F_XR, cyc + 0);
  k_sqdiff<<<256, 256, 0, stream>>>(out + Z_Y, out + F_YR, cyc + 1);
  k_finish<<<1, 64, 0, stream>>>(cyc, out + CYC_X, out + CYC_Y);
}

// Round 4
// 1935.728 us; speedup vs baseline: 1.4383x; 1.1589x over previous
//
#include <hip/hip_runtime.h>

// ============================================================================
// MUCRP_17265768530653 — cross-domain VAE forward on MI355X (gfx950)
// Round 4:
//  - re-encoders fused algebraically: enc(dec(z)) via Wcomb = W4@W1 (no relu
//    between) -> removes two ~100MB-read GEMMs + partial round-trips
//  - twin kernels batched into single launches (blockIdx.y/z arg select)
//  - FGW: kbuild also accumulates b_raw (saves 1 matvec/iter); matvecs carry
//    raw denominators with on-the-fly normalization
//  - decoder GEMMs paired by shared W4 panel, moved to the end
// ============================================================================

#define DEVI __device__ __forceinline__

typedef __attribute__((ext_vector_type(4))) float  f32x4;
typedef __attribute__((ext_vector_type(4))) short  s16x4;
typedef __attribute__((ext_vector_type(8))) short  s16x8;
typedef __attribute__((ext_vector_type(8))) __bf16 bf16x8;

DEVI short f2bf(float f) {              // RNE f32 -> bf16 (bits)
  unsigned u = __float_as_uint(f);
  u += 0x7fffu + ((u >> 16) & 1u);
  return (short)(u >> 16);
}
DEVI float bf2f(unsigned short u) { return __uint_as_float(((unsigned)u) << 16); }

DEVI f32x4 mfma16(bf16x8 a, bf16x8 b, f32x4 c) {
  return __builtin_amdgcn_mfma_f32_16x16x32_bf16(a, b, c, 0, 0, 0);
}

// ---------------------------------------------------------------------------
// Generic tiled MFMA GEMM body (verified in R1/R3).
// A: f32 row-major [M][lda].  B: bf16 TRANSPOSED [N][ldbt] (k fast).
// ---------------------------------------------------------------------------
struct GemmArgs {
  const float* Af;
  const unsigned short* Bt;
  float* outF;
  const float* bias;
  float* partials;
  int M, N, K;
  int lda, ldbt, ldc;
  int totSteps, nSplits;
};

enum { EPI_PARTIAL, EPI_BIAS, EPI_BF16, EPI_COST, EPI_LOSS };

template<int BM, int BN, int WR, int WC, int EPI>
DEVI void gemm_body(const GemmArgs g)
{
  constexpr int BK = 64, BKP = 72;
  constexpr int NT = WR * WC * 64;
  __shared__ short As[BM * BKP];
  __shared__ short Bs[BN * BKP];

  const int m0 = blockIdx.x * BM;
  int n0 = 0, kb0 = 0, kb1 = g.K, split = 0;
  if constexpr (EPI == EPI_PARTIAL) {
    split = blockIdx.y;
    int s0 = (split * g.totSteps) / g.nSplits;
    int s1 = ((split + 1) * g.totSteps) / g.nSplits;
    kb0 = s0 * BK;
    kb1 = s1 * BK; if (kb1 > g.K) kb1 = g.K;
  } else {
    n0 = blockIdx.y * BN;
  }
  const int tid  = threadIdx.x;
  const int lane = tid & 63;
  const int wv   = tid >> 6;
  const int wr   = wv % WR;
  const int wc   = wv / WR;

  f32x4 acc[2][4];
  #pragma unroll
  for (int i = 0; i < 2; ++i)
    #pragma unroll
    for (int j = 0; j < 4; ++j) acc[i][j] = f32x4{0.f, 0.f, 0.f, 0.f};

  for (int kb = kb0; kb < kb1; kb += BK) {
    {   // stage A (f32 -> bf16)
      constexpr int NV = BM * BK / 4;
      #pragma unroll
      for (int i = 0; i < NV / NT; ++i) {
        int idx = tid + NT * i;
        int r = idx >> 4, q = idx & 15;
        int k = kb + 4 * q;
        f32x4 v = f32x4{0.f, 0.f, 0.f, 0.f};
        if (k < kb1) v = *(const f32x4*)(g.Af + (size_t)(m0 + r) * g.lda + k);
        s16x4 s;
        s.x = f2bf(v.x); s.y = f2bf(v.y); s.z = f2bf(v.z); s.w = f2bf(v.w);
        *(s16x4*)&As[r * BKP + 4 * q] = s;
      }
    }
    {   // stage B (bf16 [N][K])
      constexpr int NV = BN * BK / 8;
      #pragma unroll
      for (int i = 0; i < NV / NT; ++i) {
        int idx = tid + NT * i;
        int r = idx >> 3, q = idx & 7;
        int k = kb + 8 * q;
        s16x8 v{};
        if ((n0 + r) < g.N && k < kb1)
          v = *(const s16x8*)(g.Bt + (size_t)(n0 + r) * g.ldbt + k);
        *(s16x8*)&Bs[r * BKP + 8 * q] = v;
      }
    }
    __syncthreads();
    #pragma unroll
    for (int s = 0; s < 2; ++s) {
      const int ko = 32 * s + 8 * (lane >> 4);
      bf16x8 a0 = *(const bf16x8*)&As[(wr * 32 +      (lane & 15)) * BKP + ko];
      bf16x8 a1 = *(const bf16x8*)&As[(wr * 32 + 16 + (lane & 15)) * BKP + ko];
      #pragma unroll
      for (int fn = 0; fn < 4; ++fn) {
        bf16x8 b = *(const bf16x8*)&Bs[(wc * 64 + fn * 16 + (lane & 15)) * BKP + ko];
        acc[0][fn] = mfma16(a0, b, acc[0][fn]);
        acc[1][fn] = mfma16(a1, b, acc[1][fn]);
      }
    }
    __syncthreads();
  }

  #pragma unroll
  for (int fm = 0; fm < 2; ++fm) {
    #pragma unroll
    for (int fn = 0; fn < 4; ++fn) {
      #pragma unroll
      for (int p = 0; p < 4; ++p) {
        int gm = m0 + wr * 32 + fm * 16 + (lane >> 4) * 4 + p;
        int gn = n0 + wc * 64 + fn * 16 + (lane & 15);
        float v = acc[fm][fn][p];
        if constexpr (EPI == EPI_PARTIAL) {
          g.partials[((size_t)split * g.M + gm) * 256 + gn] = v;
        } else {
          if (gn < g.N) g.outF[(size_t)gm * g.ldc + gn] = v + g.bias[gn];
        }
      }
    }
  }
}

template<int BM, int BN, int WR, int WC, int EPI>
__global__ __launch_bounds__(WR*WC*64)
void k_gemm2(GemmArgs g0, GemmArgs g1)
{
  gemm_body<BM, BN, WR, WC, EPI>(blockIdx.z ? g1 : g0);
}

// ---------------------------------------------------------------------------
// FGW 1024^3 GEMM, 4-wave (2x2) 64x64 tile, 256 blocks (verified R3).
// EPI_COST additionally zeroes braw (block 0) for the following kbuild.
// ---------------------------------------------------------------------------
struct FgwGemmArgs {
  const unsigned short* A;
  const unsigned short* Bt;
  unsigned short* U;
  float* cost;
  const float* f1;
  const float* f2;
  const float* cpp;
  const float* tran;
  unsigned* mx;
  float* loss;
  float* braw;
};

template<int EPI>
__global__ __launch_bounds__(256)
void k_fgw_gemm(FgwGemmArgs a)
{
  __shared__ short As[64 * 72];
  __shared__ short Bs[64 * 72];
  __shared__ float red[4];

  const int bid = blockIdx.x, tid = threadIdx.x;
  const int lane = tid & 63, wv = tid >> 6;
  const int wr = wv & 1, wc = wv >> 1;
  const int m0 = (bid >> 4) * 64, n0 = (bid & 15) * 64;

  if constexpr (EPI == EPI_COST) {
    if (bid == 0) {
      #pragma unroll
      for (int i = 0; i < 4; ++i) a.braw[tid + 256 * i] = 0.f;
    }
  }

  f32x4 acc[2][2];
  #pragma unroll
  for (int i = 0; i < 2; ++i)
    #pragma unroll
    for (int j = 0; j < 2; ++j) acc[i][j] = f32x4{0.f, 0.f, 0.f, 0.f};

  for (int kb = 0; kb < 1024; kb += 64) {
    #pragma unroll
    for (int i = 0; i < 2; ++i) {
      int idx = tid + 256 * i;
      int r = idx >> 3, q = idx & 7;
      *(s16x8*)&As[r * 72 + 8 * q] = *(const s16x8*)&a.A [(size_t)(m0 + r) * 1024 + kb + 8 * q];
      *(s16x8*)&Bs[r * 72 + 8 * q] = *(const s16x8*)&a.Bt[(size_t)(n0 + r) * 1024 + kb + 8 * q];
    }
    __syncthreads();
    #pragma unroll
    for (int s = 0; s < 2; ++s) {
      const int ko = 32 * s + 8 * (lane >> 4);
      bf16x8 a0 = *(const bf16x8*)&As[(wr * 32 +      (lane & 15)) * 72 + ko];
      bf16x8 a1 = *(const bf16x8*)&As[(wr * 32 + 16 + (lane & 15)) * 72 + ko];
      bf16x8 b0 = *(const bf16x8*)&Bs[(wc * 32 +      (lane & 15)) * 72 + ko];
      bf16x8 b1 = *(const bf16x8*)&Bs[(wc * 32 + 16 + (lane & 15)) * 72 + ko];
      acc[0][0] = mfma16(a0, b0, acc[0][0]);
      acc[1][0] = mfma16(a1, b0, acc[1][0]);
      acc[0][1] = mfma16(a0, b1, acc[0][1]);
      acc[1][1] = mfma16(a1, b1, acc[1][1]);
    }
    __syncthreads();
  }

  float lred = 0.f;
  #pragma unroll
  for (int fm = 0; fm < 2; ++fm) {
    #pragma unroll
    for (int fn = 0; fn < 2; ++fn) {
      #pragma unroll
      for (int p = 0; p < 4; ++p) {
        int gm = m0 + wr * 32 + fm * 16 + (lane >> 4) * 4 + p;
        int gn = n0 + wc * 32 + fn * 16 + (lane & 15);
        float v = acc[fm][fn][p];
        size_t o = (size_t)gm * 1024 + gn;
        if constexpr (EPI == EPI_BF16) {
          a.U[o] = (unsigned short)f2bf(v);
        } else {
          float c = 0.1f * (a.f1[gm] + a.f2[gn] - 2.f * v) + 0.9f * a.cpp[o];
          if constexpr (EPI == EPI_COST) {
            a.cost[o] = c;
            lred = fmaxf(lred, fabsf(c));
          } else {
            lred += c * a.tran[o];
          }
        }
      }
    }
  }
  if constexpr (EPI != EPI_BF16) {
    #pragma unroll
    for (int off = 32; off; off >>= 1) {
      float t = __shfl_xor(lred, off, 64);
      lred = (EPI == EPI_COST) ? fmaxf(lred, t) : (lred + t);
    }
    if (lane == 0) red[wv] = lred;
    __syncthreads();
    if (tid == 0) {
      if constexpr (EPI == EPI_COST) {
        float t = fmaxf(fmaxf(red[0], red[1]), fmaxf(red[2], red[3]));
        atomicMax(a.mx, __float_as_uint(t));
      } else {
        atomicAdd(a.loss, red[0] + red[1] + red[2] + red[3]);
      }
    }
  }
}

// ---------------------------------------------------------------------------
// kbuild: K = exp(-cost/mx)*tran, KT, and braw[c] += sum_r K[r][c]*(ps/draw[r])
// ---------------------------------------------------------------------------
__global__ __launch_bounds__(256)
void k_kbuild(const float* cost, const float* tran, const unsigned* mxbits,
              const float* draw, float* braw, float* K, float* KT)
{
  __shared__ float t[64 * 65];
  __shared__ float dualS[64];
  __shared__ float csum[4][64];
  const int r0 = blockIdx.x * 64, c0 = blockIdx.y * 64;
  const int tid = threadIdx.x;
  const float inv = 1.f / __uint_as_float(*mxbits);
  const float PS = 1.f / 1024.f;
  if (tid < 64) dualS[tid] = PS / draw[r0 + tid];
  __syncthreads();
  float colpart = 0.f;
  #pragma unroll
  for (int i = 0; i < 16; ++i) {
    int idx = tid + 256 * i;
    int r = idx >> 6, c = idx & 63;
    size_t o = (size_t)(r0 + r) * 1024 + (c0 + c);
    float v = expf(-cost[o] * inv) * tran[o];
    K[o] = v;
    t[r * 65 + c] = v;
    colpart += v * dualS[r];
  }
  csum[tid >> 6][tid & 63] = colpart;
  __syncthreads();
  #pragma unroll
  for (int i = 0; i < 16; ++i) {
    int idx = tid + 256 * i;
    int c = idx >> 6, r = idx & 63;
    KT[(size_t)(c0 + c) * 1024 + (r0 + r)] = t[r * 65 + c];
  }
  if (tid < 64)
    atomicAdd(&braw[c0 + tid],
              csum[0][tid] + csum[1][tid] + csum[2][tid] + csum[3][tid]);
}

// y_raw[r] = M[r,:] . (C/x_raw)  (raw denominators; consumer divides)
__global__ __launch_bounds__(256)
void k_matvec(const float* M, const float* xraw, float* yraw)
{
  const int r = blockIdx.x * 4 + (threadIdx.x >> 6);
  const int lane = threadIdx.x & 63;
  const float C = 1.f / 1024.f;
  const f32x4* row = (const f32x4*)(M + (size_t)r * 1024);
  const f32x4* xv  = (const f32x4*)xraw;
  float s = 0.f;
  #pragma unroll
  for (int q = 0; q < 4; ++q) {
    f32x4 a = row[lane + 64 * q];
    f32x4 x = xv [lane + 64 * q];
    s += a.x * (C / x.x) + a.y * (C / x.y) + a.z * (C / x.z) + a.w * (C / x.w);
  }
  #pragma unroll
  for (int o = 32; o; o >>= 1) s += __shfl_xor(s, o, 64);
  if (lane == 0) yraw[r] = s;
}

// tran = (ps/draw[r])*(pt/braw[c])*K ; emit tran^T bf16; NaN-flag on last iter
__global__ __launch_bounds__(256)
void k_tranupd(const float* K, const float* draw, const float* braw,
               float* tran, unsigned short* tranT, unsigned* flag, int check)
{
  __shared__ float t[64 * 65];
  __shared__ float dualS[64], bS[64];
  const int r0 = blockIdx.x * 64, c0 = blockIdx.y * 64;
  const int tid = threadIdx.x;
  const float P = 1.f / 1024.f;
  if (tid < 64) dualS[tid] = P / draw[r0 + tid];
  else if (tid < 128) bS[tid - 64] = P / braw[c0 + tid - 64];
  __syncthreads();
  unsigned bad = 0;
  #pragma unroll
  for (int i = 0; i < 16; ++i) {
    int idx = tid + 256 * i;
    int r = idx >> 6, c = idx & 63;
    size_t o = (size_t)(r0 + r) * 1024 + (c0 + c);
    float v = dualS[r] * bS[c] * K[o];
    tran[o] = v;
    t[r * 65 + c] = v;
    if (v != v) bad = 1u;
  }
  __syncthreads();
  #pragma unroll
  for (int i = 0; i < 16; ++i) {
    int idx = tid + 256 * i;
    int c = idx >> 6, r = idx & 63;
    tranT[(size_t)(c0 + c) * 1024 + (r0 + r)] = (unsigned short)f2bf(t[r * 65 + c]);
  }
  if (check && bad) atomicOr(flag, 1u);
}

// ---------------------------------------------------------------------------
// batched f32 [R][C] -> bf16 [C][R] transpose (4 weight matrices, one launch)
// ---------------------------------------------------------------------------
struct T4 { const float* in[4]; unsigned short* out[4]; int R[4], C[4], nx[4], nt[4]; };
__global__ void k_transpose4(T4 d)
{
  __shared__ float t[64][65];
  const int z = blockIdx.y;
  const int tile = blockIdx.x;
  if (tile >= d.nt[z]) return;
  const int R = d.R[z], C = d.C[z];
  const int r0 = (tile % d.nx[z]) * 64, c0 = (tile / d.nx[z]) * 64;
  const float* in = d.in[z];
  unsigned short* out = d.out[z];
  const int tid = threadIdx.x;
  #pragma unroll
  for (int i = 0; i < 16; ++i) {
    int idx = tid + 256 * i;
    int r = idx >> 6, c = idx & 63;
    float v = 0.f;
    if ((r0 + r) < R && (c0 + c) < C) v = in[(size_t)(r0 + r) * C + (c0 + c)];
    t[r][c] = v;
  }
  __syncthreads();
  #pragma unroll
  for (int i = 0; i < 16; ++i) {
    int idx = tid + 256 * i;
    int c = idx >> 6, r = idx & 63;
    if ((c0 + c) < C && (r0 + r) < R)
      out[(size_t)(c0 + c) * R + (r0 + r)] = (unsigned short)f2bf(t[r][c]);
  }
}

// Wcomb partial reduce + transpose: WcT[v][u] = f2bf(sum_p partials[p][u][v])
__global__ void k_wcomb_reduce(const float* partials, unsigned short* WcTa,
                               unsigned short* WcTb)
{
  __shared__ float t[64][65];
  const int z = blockIdx.z;
  const float* P = partials + (size_t)z * 32 * 256 * 256;
  unsigned short* WcT = z ? WcTb : WcTa;
  const int u0 = blockIdx.x * 64, v0 = blockIdx.y * 64;
  const int tid = threadIdx.x;
  #pragma unroll
  for (int i = 0; i < 16; ++i) {
    int idx = tid + 256 * i;
    int u = idx >> 6, v = idx & 63;
    float s = 0.f;
    for (int p = 0; p < 32; ++p)
      s += P[(size_t)p * 65536 + (u0 + u) * 256 + (v0 + v)];
    t[u][v] = s;
  }
  __syncthreads();
  #pragma unroll
  for (int i = 0; i < 16; ++i) {
    int idx = tid + 256 * i;
    int v = idx >> 6, u = idx & 63;
    WcT[(size_t)(v0 + v) * 256 + (u0 + u)] = (unsigned short)f2bf(t[u][v]);
  }
}

// bc[c] = b4 . Wt1[c,:] + b1[c]   (combined re-encode bias)
struct BcArgs {
  const float* b4[2]; const unsigned short* Wt1[2]; const float* b1[2];
  float* bc[2]; int K[2];
};
__global__ void k_bcvec(BcArgs a)
{
  const int y = blockIdx.y;
  const int c = blockIdx.x * 4 + (threadIdx.x >> 6);
  const int lane = threadIdx.x & 63;
  const int K = a.K[y];
  const unsigned short* wrow = a.Wt1[y] + (size_t)c * K;
  const float* b4 = a.b4[y];
  float s = 0.f;
  for (int k = lane * 8; k < K; k += 512) {
    s16x8 w = *(const s16x8*)&wrow[k];
    f32x4 v0 = *(const f32x4*)&b4[k];
    f32x4 v1 = *(const f32x4*)&b4[k + 4];
    s += v0.x * bf2f((unsigned short)w[0]) + v0.y * bf2f((unsigned short)w[1])
       + v0.z * bf2f((unsigned short)w[2]) + v0.w * bf2f((unsigned short)w[3])
       + v1.x * bf2f((unsigned short)w[4]) + v1.y * bf2f((unsigned short)w[5])
       + v1.z * bf2f((unsigned short)w[6]) + v1.w * bf2f((unsigned short)w[7]);
  }
  #pragma unroll
  for (int o = 32; o; o >>= 1) s += __shfl_xor(s, o, 64);
  if (lane == 0) a.bc[y][c] = s + a.b1[y][c];
}

// batched split-K reduce + bias + relu
struct Red2 { const float* partials[2]; const float* bias[2]; float* h[2]; int ns; };
__global__ void k_reduce2(Red2 a)
{
  const int y = blockIdx.y;
  int idx = blockIdx.x * 256 + threadIdx.x;
  float s = a.bias[y][idx & 255];
  const float* P = a.partials[y];
  for (int p = 0; p < a.ns; ++p) s += P[(size_t)p * (1024 * 256) + idx];
  a.h[y][idx] = fmaxf(s, 0.f);
}

// batched encoder head (2 sides)
struct EH2 {
  const float* h[2]; const float* W21[2]; const float* b21[2];
  const float* W22[2]; const float* b22[2]; const float* eps[2];
  float* mu[2]; float* lv[2]; float* zO[2];
};
__global__ void k_enc_head2(EH2 a)
{
  __shared__ float hrow[256];
  __shared__ float res[128];
  const int y = blockIdx.y;
  const int i = blockIdx.x;
  const int t = threadIdx.x;                  // 128
  hrow[t]       = a.h[y][(size_t)i * 256 + t];
  hrow[t + 128] = a.h[y][(size_t)i * 256 + t + 128];
  __syncthreads();
  const int c = t & 63;
  const float* W = (t < 64) ? a.W21[y] : a.W22[y];
  float acc = (t < 64) ? a.b21[y][c] : a.b22[y][c];
  #pragma unroll 8
  for (int j = 0; j < 256; ++j) acc += hrow[j] * W[j * 64 + c];
  res[t] = acc;
  __syncthreads();
  if (t < 64) {
    float mu = res[t], lv = res[64 + t];
    a.mu[y][(size_t)i * 64 + t] = mu;
    a.lv[y][(size_t)i * 64 + t] = lv;
    a.zO[y][(size_t)i * 64 + t] = mu + a.eps[y][(size_t)i * 64 + t] * expf(0.5f * lv);
  }
}

// fused re-encode: feature = head(relu(hd @ Wcomb + bc)) + eps reparam
struct RencArgs {
  const float* hd[2]; const unsigned short* WcT[2]; const float* bc[2];
  const float* W21[2]; const float* b21[2]; const float* W22[2]; const float* b22[2];
  const float* eps[2]; float* fout[2];
};
__global__ void k_renc_head(RencArgs a)
{
  __shared__ float hdrow[256];
  __shared__ float hr[256];
  __shared__ float res[128];
  const int y = blockIdx.y;
  const int i = blockIdx.x;
  const int t = threadIdx.x;                  // 256
  hdrow[t] = a.hd[y][(size_t)i * 256 + t];
  __syncthreads();
  {
    const s16x8* wr = (const s16x8*)(a.WcT[y] + (size_t)t * 256);
    float s = a.bc[y][t];
    #pragma unroll 4
    for (int j = 0; j < 32; ++j) {
      s16x8 w = wr[j];
      const float* hp = &hdrow[j * 8];
      s += hp[0] * bf2f((unsigned short)w[0]) + hp[1] * bf2f((unsigned short)w[1])
         + hp[2] * bf2f((unsigned short)w[2]) + hp[3] * bf2f((unsigned short)w[3])
         + hp[4] * bf2f((unsigned short)w[4]) + hp[5] * bf2f((unsigned short)w[5])
         + hp[6] * bf2f((unsigned short)w[6]) + hp[7] * bf2f((unsigned short)w[7]);
    }
    hr[t] = fmaxf(s, 0.f);
  }
  __syncthreads();
  if (t < 128) {
    const int c = t & 63;
    const float* W = (t < 64) ? a.W21[y] : a.W22[y];
    float acc = (t < 64) ? a.b21[y][c] : a.b22[y][c];
    #pragma unroll 8
    for (int j = 0; j < 256; ++j) acc += hr[j] * W[j * 64 + c];
    res[t] = acc;
  }
  __syncthreads();
  if (t < 64) {
    float mu = res[t], lv = res[64 + t];
    a.fout[y][(size_t)i * 64 + t] = mu + a.eps[y][(size_t)i * 64 + t] * expf(0.5f * lv);
  }
}

// batched decoder heads: hd = relu(z @ W3 + b3), 4 variants
struct DH4 { const float* z[4]; const float* W3[4]; const float* b3[4]; float* hd[4]; };
__global__ void k_dec_head4(DH4 a)
{
  __shared__ float zrow[64];
  const int y = blockIdx.y;
  const int i = blockIdx.x;
  const int t = threadIdx.x;                  // 256
  if (t < 64) zrow[t] = a.z[y][(size_t)i * 64 + t];
  __syncthreads();
  const float* W3 = a.W3[y];
  float acc = a.b3[y][t];
  #pragma unroll
  for (int d = 0; d < 64; ++d) acc += zrow[d] * W3[d * 256 + t];
  a.hd[y][(size_t)i * 256 + t] = fmaxf(acc, 0.f);
}

// ---------------------------------------------------------------------------
// batched _distance_gmm (3 variants in one launch)
// ---------------------------------------------------------------------------
struct D3 {
  const float* xmu[3]; const float* xlv[3]; const float* ymu[3]; const float* ylv[3];
  unsigned short* outB[3]; float* outF[3]; float* frow[3]; int wbf[3]; int dof[3];
};
__global__ void k_dist3(D3 d)
{
  __shared__ float SX[64 * 68];
  __shared__ float SY[64 * 68];
  const int z = blockIdx.z;
  const int r0 = blockIdx.x * 64, c0 = blockIdx.y * 64;
  const int t = threadIdx.x;                  // 256
  const int rr = t >> 2;
  const int c4 = (t & 3) * 16;
  const float* xmu = d.xmu[z]; const float* xlv = d.xlv[z];
  const float* ymu = d.ymu[z]; const float* ylv = d.ylv[z];
  float acc[16];
  #pragma unroll
  for (int i = 0; i < 16; ++i) acc[i] = 0.f;

  for (int pass = 0; pass < 2; ++pass) {
    __syncthreads();
    #pragma unroll
    for (int i = 0; i < 16; ++i) {
      int idx = t + 256 * i;
      int r = idx >> 6, dd = idx & 63;
      float vx, vy;
      if (pass == 0) {
        vx = xmu[(size_t)(r0 + r) * 64 + dd];
        vy = ymu[(size_t)(c0 + r) * 64 + dd];
      } else {
        vx = expf(0.5f * xlv[(size_t)(r0 + r) * 64 + dd]);
        vy = expf(0.5f * ylv[(size_t)(c0 + r) * 64 + dd]);
      }
      SX[r * 68 + dd] = vx;
      SY[r * 68 + dd] = vy;
    }
    __syncthreads();
    #pragma unroll
    for (int i = 0; i < 16; ++i) {
      int cc = c4 + i;
      float s = 0.f;
      #pragma unroll
      for (int d4 = 0; d4 < 16; ++d4) {
        f32x4 av = *(const f32x4*)&SX[rr * 68 + 4 * d4];
        f32x4 bv = *(const f32x4*)&SY[cc * 68 + 4 * d4];
        f32x4 df = av - bv;
        s += df.x * df.x + df.y * df.y + df.z * df.z + df.w * df.w;
      }
      acc[i] += s;
    }
  }
  float fpart = 0.f;
  #pragma unroll
  for (int i = 0; i < 16; ++i) {
    int cc = c4 + i;
    float val = acc[i] + 1e-6f;
    if (d.wbf[z]) d.outB[z][(size_t)(r0 + rr) * 1024 + (c0 + cc)] = (unsigned short)f2bf(val);
    else          d.outF[z][(size_t)(r0 + rr) * 1024 + (c0 + cc)] = val;
    if (d.dof[z]) fpart += val * val;
  }
  if (d.dof[z]) {
    fpart += __shfl_xor(fpart, 1, 64);
    fpart += __shfl_xor(fpart, 2, 64);
    if ((t & 3) == 0) atomicAdd(d.frow[z] + (r0 + rr), fpart * (1.f / 1024.f));
  }
}

// init: tran/tranT/draw/braw/f1/f2/mx/nanflag/cyc/out-scalars
__global__ void k_init(float* tran, unsigned short* tranT, float* draw, float* braw,
                       float* f1, float* f2, unsigned* mx, unsigned* nanflag,
                       float* cyc, float* ga, float* gb, float* al)
{
  const int bid = blockIdx.x, tid = threadIdx.x;   // 1024 x 256
  const float v = 1.f / (1024.f * 1024.f);
  const unsigned short vb = (unsigned short)f2bf(v);
  const size_t base = (size_t)bid * 1024;
  #pragma unroll
  for (int i = 0; i < 4; ++i) {
    tran [base + tid + 256 * i] = v;
    tranT[base + tid + 256 * i] = vb;
  }
  if (bid == 0) {
    #pragma unroll
    for (int i = 0; i < 4; ++i) {
      int k = tid + 256 * i;
      draw[k] = 1.f; braw[k] = 0.f; f1[k] = 0.f; f2[k] = 0.f;
    }
    if (tid < 16) mx[tid] = 0u;
    if (tid == 0) { *nanflag = 0u; cyc[0] = 0.f; cyc[1] = 0.f; *ga = 0.f; *gb = 0.f; *al = 0.f; }
  }
}

__global__ void k_nanfix(float* tran, unsigned short* tranT, const unsigned* flag)
{
  if (*flag == 0u) return;
  const int bid = blockIdx.x, tid = threadIdx.x;   // 1024 x 256
  const float v = 1.f / (1024.f * 1024.f);
  const unsigned short vb = (unsigned short)f2bf(v);
  const size_t base = (size_t)bid * 1024;
  #pragma unroll
  for (int i = 0; i < 4; ++i) {
    tran [base + tid + 256 * i] = v;
    tranT[base + tid + 256 * i] = vb;
  }
}

// batched GMM KL (2 sides)
struct G2 {
  const float* z[2]; const float* mu[2]; const float* lv[2];
  const float* pmu[2]; const float* plv[2]; float* o[2];
};
__global__ void k_gmm2(G2 a)
{
  const int y = blockIdx.y;
  const int i = blockIdx.x;
  const int d = threadIdx.x;                  // 64
  const float zd = a.z[y][(size_t)i * 64 + d];
  const float m  = a.mu[y][(size_t)i * 64 + d];
  const float l  = a.lv[y][(size_t)i * 64 + d];
  float t = l + (zd - m) * (zd - m) * expf(-l);
  #pragma unroll
  for (int o = 32; o; o >>= 1) t += __shfl_xor(t, o, 64);
  const float C0 = 64.f * 1.8378770664093453f;
  float logq = -0.5f * (C0 + t);
  float lp[20];
  #pragma unroll
  for (int k = 0; k < 20; ++k) {
    float pm = a.pmu[y][k * 64 + d], pl = a.plv[y][k * 64 + d];
    float u = pl + (zd - pm) * (zd - pm) * expf(-pl);
    #pragma unroll
    for (int o = 32; o; o >>= 1) u += __shfl_xor(u, o, 64);
    lp[k] = -0.5f * (C0 + u);
  }
  float mx = lp[0];
  #pragma unroll
  for (int k = 1; k < 20; ++k) mx = fmaxf(mx, lp[k]);
  float s = 0.f;
  #pragma unroll
  for (int k = 0; k < 20; ++k) s += expf(lp[k] - mx);
  float logp = mx + logf(s) - 2.9957322735539909f;
  if (d == 0) atomicAdd(a.o[y], logq - logp);
}

struct Sq2 { const float* a[2]; const float* b[2]; float* cyc; };
__global__ void k_sqdiff2(Sq2 g)
{
  __shared__ float red[4];
  const int y = blockIdx.y;
  int idx = blockIdx.x * 256 + threadIdx.x;
  float d = g.a[y][idx] - g.b[y][idx];
  d = d * d;
  #pragma unroll
  for (int o = 32; o; o >>= 1) d += __shfl_xor(d, o, 64);
  int lane = threadIdx.x & 63, wv = threadIdx.x >> 6;
  if (lane == 0) red[wv] = d;
  __syncthreads();
  if (threadIdx.x == 0) atomicAdd(g.cyc + y, red[0] + red[1] + red[2] + red[3]);
}

__global__ void k_finish(const float* slots, float* o1, float* o2)
{
  if (threadIdx.x == 0) { *o1 = sqrtf(slots[0]); *o2 = sqrtf(slots[1]); }
}

// ---------------------------------------------------------------------------
extern "C" void kernel_launch(void* const* d_in, const int* in_sizes, int n_in,
                              void* d_out, int out_size, void* d_ws, size_t ws_size,
                              hipStream_t stream)
{
  (void)in_sizes; (void)n_in; (void)out_size; (void)ws_size;

  const float* X     = (const float*)d_in[2];
  const float* Y     = (const float*)d_in[3];
  const float* pmua  = (const float*)d_in[4];
  const float* plva  = (const float*)d_in[5];
  const float* pmub  = (const float*)d_in[6];
  const float* plvb  = (const float*)d_in[7];
  const float* epsx  = (const float*)d_in[8];
  const float* epsy  = (const float*)d_in[9];
  const float* epsxr = (const float*)d_in[10];
  const float* epsyr = (const float*)d_in[11];
  const float* W1a = (const float*)d_in[12];  const float* b1a = (const float*)d_in[13];
  const float* W21a= (const float*)d_in[14];  const float* b21a= (const float*)d_in[15];
  const float* W22a= (const float*)d_in[16];  const float* b22a= (const float*)d_in[17];
  const float* W3a = (const float*)d_in[18];  const float* b3a = (const float*)d_in[19];
  const float* W4a = (const float*)d_in[20];  const float* b4a = (const float*)d_in[21];
  const float* W1b = (const float*)d_in[22];  const float* b1b = (const float*)d_in[23];
  const float* W21b= (const float*)d_in[24];  const float* b21b= (const float*)d_in[25];
  const float* W22b= (const float*)d_in[26];  const float* b22b= (const float*)d_in[27];
  const float* W3b = (const float*)d_in[28];  const float* b3b = (const float*)d_in[29];
  const float* W4b = (const float*)d_in[30];  const float* b4b = (const float*)d_in[31];

  float* out = (float*)d_out;
  const size_t P_X = 0, P_Y = 20480000, P_X2Y = 46080000, P_Y2X = 71680000;
  const size_t Z_X = 92160000, Z_Y = 92225536;
  const size_t GMM_A = 92291072, GMM_B = 92291073;
  const size_t F_XR = 92291074, F_YR = 92356610;
  const size_t ALIGN = 92422146, CYC_X = 92422147, CYC_Y = 92422148;

  // ---- workspace carve (~82 MB)
  char* w = (char*)d_ws;
  size_t off = 0;
  auto alloc = [&](size_t bytes) -> void* {
    void* p = w + off;
    off += (bytes + 255) & ~(size_t)255;
    return p;
  };
  unsigned short* Wt1a = (unsigned short*)alloc((size_t)256 * 20000 * 2);
  unsigned short* Wt1b = (unsigned short*)alloc((size_t)256 * 25000 * 2);
  unsigned short* W4ta = (unsigned short*)alloc((size_t)20000 * 256 * 2);
  unsigned short* W4tb = (unsigned short*)alloc((size_t)25000 * 256 * 2);
  unsigned short* WcTa = (unsigned short*)alloc((size_t)256 * 256 * 2);
  unsigned short* WcTb = (unsigned short*)alloc((size_t)256 * 256 * 2);
  float* bca  = (float*)alloc(256 * 4);
  float* bcb  = (float*)alloc(256 * 4);
  float* h0   = (float*)alloc((size_t)1024 * 256 * 4);
  float* h1   = (float*)alloc((size_t)1024 * 256 * 4);
  float* mu_a = (float*)alloc(1024 * 64 * 4);
  float* lv_a = (float*)alloc(1024 * 64 * 4);
  float* mu_b = (float*)alloc(1024 * 64 * 4);
  float* lv_b = (float*)alloc(1024 * 64 * 4);
  float* f1   = (float*)alloc(1024 * 4);
  float* f2   = (float*)alloc(1024 * 4);
  unsigned* mx      = (unsigned*)alloc(16 * 4);
  unsigned* nanflag = (unsigned*)alloc(256);
  float* cyc  = (float*)alloc(256);
  float* draw = (float*)alloc(1024 * 4);
  float* braw = (float*)alloc(1024 * 4);
  // arena (32.5 MB), sequentially reused:
  //   phase W: Wcomb partials (16 MB) | phase E: enc partials (32 MB)
  //   phase F: FGW matrices (28 MB)   | phase D: hdec buffers (4 MB)
  char* arena = (char*)alloc((size_t)3406 * 9957 + 32 * 1024 * 1024 - (size_t)3406 * 9957);
  float* partials = (float*)arena;
  size_t ao = 0;
  auto aalloc = [&](size_t bytes) -> void* {
    void* p = arena + ao;
    ao += (bytes + 255) & ~(size_t)255;
    return p;
  };
  unsigned short* cpostB  = (unsigned short*)aalloc((size_t)1024 * 1024 * 2);
  unsigned short* cpriorB = (unsigned short*)aalloc((size_t)1024 * 1024 * 2);
  float* cpp  = (float*)aalloc((size_t)1024 * 1024 * 4);
  float* tran = (float*)aalloc((size_t)1024 * 1024 * 4);
  unsigned short* tranT = (unsigned short*)aalloc((size_t)1024 * 1024 * 2);
  unsigned short* Umat  = (unsigned short*)aalloc((size_t)1024 * 1024 * 2);
  float* cost  = (float*)aalloc((size_t)1024 * 1024 * 4);
  float* Kmat  = (float*)aalloc((size_t)1024 * 1024 * 4);
  float* KTmat = (float*)aalloc((size_t)1024 * 1024 * 4);
  // hdec buffers alias the arena (used only after FGW is done)
  float* hd0 = (float*)(arena);
  float* hd1 = (float*)(arena + (size_t)1024 * 256 * 4);
  float* hd2 = (float*)(arena + (size_t)2 * 1024 * 256 * 4);
  float* hd3 = (float*)(arena + (size_t)3 * 1024 * 256 * 4);

  // ---- 1. weight transposes (one launch)
  {
    T4 d{};
    d.in[0] = W1a; d.out[0] = Wt1a; d.R[0] = 20000; d.C[0] = 256;
    d.in[1] = W1b; d.out[1] = Wt1b; d.R[1] = 25000; d.C[1] = 256;
    d.in[2] = W4a; d.out[2] = W4ta; d.R[2] = 256;   d.C[2] = 20000;
    d.in[3] = W4b; d.out[3] = W4tb; d.R[3] = 256;   d.C[3] = 25000;
    for (int z = 0; z < 4; ++z) {
      d.nx[z] = (d.R[z] + 63) / 64;
      d.nt[z] = d.nx[z] * ((d.C[z] + 63) / 64);
    }
    k_transpose4<<<dim3(1564, 4), 256, 0, stream>>>(d);
  }

  // ---- 2. init
  k_init<<<1024, 256, 0, stream>>>(tran, tranT, draw, braw, f1, f2, mx, nanflag,
                                   cyc, out + GMM_A, out + GMM_B, out + ALIGN);

  // ---- 3. Wcomb = W4 @ W1 (split-K) -> WcT bf16 + combined bias
  {
    GemmArgs ga{}, gb{};
    ga.Af = W4a; ga.Bt = Wt1a; ga.partials = partials;
    ga.M = 256; ga.N = 256; ga.K = 20000; ga.lda = 20000; ga.ldbt = 20000;
    ga.totSteps = 313; ga.nSplits = 32;
    gb = ga;
    gb.Af = W4b; gb.Bt = Wt1b; gb.partials = partials + (size_t)32 * 65536;
    gb.K = 25000; gb.lda = 25000; gb.ldbt = 25000; gb.totSteps = 391;
    k_gemm2<128, 256, 4, 4, EPI_PARTIAL><<<dim3(2, 32, 2), 1024, 0, stream>>>(ga, gb);
    k_wcomb_reduce<<<dim3(4, 4, 2), 256, 0, stream>>>(partials, WcTa, WcTb);
    BcArgs bc{};
    bc.b4[0] = b4a; bc.Wt1[0] = Wt1a; bc.b1[0] = b1a; bc.bc[0] = bca; bc.K[0] = 20000;
    bc.b4[1] = b4b; bc.Wt1[1] = Wt1b; bc.b1[1] = b1b; bc.bc[1] = bcb; bc.K[1] = 25000;
    k_bcvec<<<dim3(64, 2), 256, 0, stream>>>(bc);
  }

  // ---- 4. encoders (batched, 16 K-splits each)
  {
    GemmArgs ga{}, gb{};
    ga.Af = X; ga.Bt = Wt1a; ga.partials = partials;
    ga.M = 1024; ga.N = 256; ga.K = 20000; ga.lda = 20000; ga.ldbt = 20000;
    ga.totSteps = 313; ga.nSplits = 16;
    gb = ga;
    gb.Af = Y; gb.Bt = Wt1b; gb.partials = partials + (size_t)16 * 1024 * 256;
    gb.K = 25000; gb.lda = 25000; gb.ldbt = 25000; gb.totSteps = 391;
    k_gemm2<128, 256, 4, 4, EPI_PARTIAL><<<dim3(8, 16, 2), 1024, 0, stream>>>(ga, gb);
    Red2 r{};
    r.partials[0] = partials; r.partials[1] = partials + (size_t)16 * 1024 * 256;
    r.bias[0] = b1a; r.bias[1] = b1b; r.h[0] = h0; r.h[1] = h1; r.ns = 16;
    k_reduce2<<<dim3(1024, 2), 256, 0, stream>>>(r);
    EH2 e{};
    e.h[0] = h0; e.W21[0] = W21a; e.b21[0] = b21a; e.W22[0] = W22a; e.b22[0] = b22a;
    e.eps[0] = epsx; e.mu[0] = mu_a; e.lv[0] = lv_a; e.zO[0] = out + Z_X;
    e.h[1] = h1; e.W21[1] = W21b; e.b21[1] = b21b; e.W22[1] = W22b; e.b22[1] = b22b;
    e.eps[1] = epsy; e.mu[1] = mu_b; e.lv[1] = lv_b; e.zO[1] = out + Z_Y;
    k_enc_head2<<<dim3(1024, 2), 128, 0, stream>>>(e);
  }

  // ---- 5. GMM losses (only need z/mu/lv)
  {
    G2 g{};
    g.z[0] = out + Z_X; g.mu[0] = mu_a; g.lv[0] = lv_a; g.pmu[0] = pmua; g.plv[0] = plva;
    g.o[0] = out + GMM_A;
    g.z[1] = out + Z_Y; g.mu[1] = mu_b; g.lv[1] = lv_b; g.pmu[1] = pmub; g.plv[1] = plvb;
    g.o[1] = out + GMM_B;
    k_gmm2<<<dim3(1024, 2), 64, 0, stream>>>(g);
  }

  // ---- 6. FGW(mu_b, mu_a, lv_b, lv_a)
  {
    D3 d{};
    d.xmu[0] = mu_b; d.xlv[0] = lv_b; d.ymu[0] = mu_b; d.ylv[0] = lv_b;
    d.outB[0] = cpostB; d.frow[0] = f1; d.wbf[0] = 1; d.dof[0] = 1;
    d.xmu[1] = mu_a; d.xlv[1] = lv_a; d.ymu[1] = mu_a; d.ylv[1] = lv_a;
    d.outB[1] = cpriorB; d.frow[1] = f2; d.wbf[1] = 1; d.dof[1] = 1;
    d.xmu[2] = mu_b; d.xlv[2] = lv_b; d.ymu[2] = mu_a; d.ylv[2] = lv_a;
    d.outF[2] = cpp; d.wbf[2] = 0; d.dof[2] = 0;
    k_dist3<<<dim3(16, 16, 3), 256, 0, stream>>>(d);
  }
  FgwGemmArgs fg{};
  fg.f1 = f1; fg.f2 = f2; fg.cpp = cpp; fg.loss = out + ALIGN; fg.braw = braw;
  for (int it = 0; it < 10; ++it) {
    fg.A = cpostB; fg.Bt = tranT; fg.U = Umat;
    k_fgw_gemm<EPI_BF16><<<256, 256, 0, stream>>>(fg);
    fg.A = Umat; fg.Bt = cpriorB; fg.cost = cost; fg.mx = mx + it;
    k_fgw_gemm<EPI_COST><<<256, 256, 0, stream>>>(fg);
    k_kbuild<<<dim3(16, 16), 256, 0, stream>>>(cost, tran, mx + it, draw, braw, Kmat, KTmat);
    for (int r = 0; r < 5; ++r) {
      k_matvec<<<256, 256, 0, stream>>>(Kmat,  braw, draw);
      k_matvec<<<256, 256, 0, stream>>>(KTmat, draw, braw);
    }
    k_tranupd<<<dim3(16, 16), 256, 0, stream>>>(Kmat, draw, braw, tran, tranT,
                                                nanflag, it == 9 ? 1 : 0);
  }
  k_nanfix<<<1024, 256, 0, stream>>>(tran, tranT, nanflag);
  fg.A = cpostB; fg.Bt = tranT; fg.U = Umat;
  k_fgw_gemm<EPI_BF16><<<256, 256, 0, stream>>>(fg);
  fg.A = Umat; fg.Bt = cpriorB; fg.tran = tran;
  k_fgw_gemm<EPI_LOSS><<<256, 256, 0, stream>>>(fg);

  // ---- 7. decoder heads (4 in one launch; hdec aliases arena, FGW done)
  {
    DH4 d{};
    d.z[0] = out + Z_X; d.W3[0] = W3a; d.b3[0] = b3a; d.hd[0] = hd0;   // P_X
    d.z[1] = out + Z_Y; d.W3[1] = W3a; d.b3[1] = b3a; d.hd[1] = hd1;   // P_Y2X
    d.z[2] = out + Z_Y; d.W3[2] = W3b; d.b3[2] = b3b; d.hd[2] = hd2;   // P_Y
    d.z[3] = out + Z_X; d.W3[3] = W3b; d.b3[3] = b3b; d.hd[3] = hd3;   // P_X2Y
    k_dec_head4<<<dim3(1024, 4), 256, 0, stream>>>(d);
  }

  // ---- 8. fused re-encoders (no preds read-back)
  {
    RencArgs r{};
    r.hd[0] = hd3; r.WcT[0] = WcTb; r.bc[0] = bcb;                     // enc_b(dec_b(z_x))
    r.W21[0] = W21b; r.b21[0] = b21b; r.W22[0] = W22b; r.b22[0] = b22b;
    r.eps[0] = epsxr; r.fout[0] = out + F_XR;
    r.hd[1] = hd1; r.WcT[1] = WcTa; r.bc[1] = bca;                     // enc_a(dec_a(z_y))
    r.W21[1] = W21a; r.b21[1] = b21a; r.W22[1] = W22a; r.b22[1] = b22a;
    r.eps[1] = epsyr; r.fout[1] = out + F_YR;
    k_renc_head<<<dim3(1024, 2), 256, 0, stream>>>(r);
  }

  // ---- 9. cycle losses
  {
    Sq2 s{};
    s.a[0] = out + Z_X; s.b[0] = out + F_XR;
    s.a[1] = out + Z_Y; s.b[1] = out + F_YR;
    s.cyc = cyc;
    k_sqdiff2<<<dim3(256, 2), 256, 0, stream>>>(s);
    k_finish<<<1, 64, 0, stream>>>(cyc, out + CYC_X, out + CYC_Y);
  }

  // ---- 10. decoder GEMMs (pure output writes, batched by shared W4 panel)
  {
    GemmArgs ga{}, gb{};
    ga.Af = hd0; ga.Bt = W4ta; ga.outF = out + P_X; ga.bias = b4a;
    ga.M = 1024; ga.N = 20000; ga.K = 256; ga.lda = 256; ga.ldbt = 256; ga.ldc = 20000;
    gb = ga; gb.Af = hd1; gb.outF = out + P_Y2X;
    k_gemm2<128, 256, 4, 4, EPI_BIAS><<<dim3(8, 79, 2), 1024, 0, stream>>>(ga, gb);

    GemmArgs gc{}, gd{};
    gc.Af = hd2; gc.Bt = W4tb; gc.outF = out + P_Y; gc.bias = b4b;
    gc.M = 1024; gc.N = 25000; gc.K = 256; gc.lda = 256; gc.ldbt = 256; gc.ldc = 25000;
    gd = gc; gd.Af = hd3; gd.outF = out + P_X2Y;
    k_gemm2<128, 256, 4, 4, EPI_BIAS><<<dim3(8, 98, 2), 1024, 0, stream>>>(gc, gd);
  }
}

// Round 5
// 1548.883 us; speedup vs baseline: 1.7975x; 1.2498x over previous
//
#include <hip/hip_runtime.h>

// ============================================================================
// MUCRP_17265768530653 — cross-domain VAE forward on MI355X (gfx950)
// Round 5: k_dist3 (390us, LDS-bound, 1.9e7 bank conflicts) replaced by
// MFMA expanded-form distance: featprep (bf16 [mu,sigma] + rounded norms)
// + 4-wave 64x64 K=128 GEMM tile with fused norm/f-row epilogue (~12us).
// Rest identical to R4 (passed, 1936us).
// ============================================================================

#define DEVI __device__ __forceinline__

typedef __attribute__((ext_vector_type(4))) float  f32x4;
typedef __attribute__((ext_vector_type(4))) short  s16x4;
typedef __attribute__((ext_vector_type(8))) short  s16x8;
typedef __attribute__((ext_vector_type(8))) __bf16 bf16x8;

DEVI short f2bf(float f) {              // RNE f32 -> bf16 (bits)
  unsigned u = __float_as_uint(f);
  u += 0x7fffu + ((u >> 16) & 1u);
  return (short)(u >> 16);
}
DEVI float bf2f(unsigned short u) { return __uint_as_float(((unsigned)u) << 16); }

DEVI f32x4 mfma16(bf16x8 a, bf16x8 b, f32x4 c) {
  return __builtin_amdgcn_mfma_f32_16x16x32_bf16(a, b, c, 0, 0, 0);
}

// ---------------------------------------------------------------------------
// Generic tiled MFMA GEMM body (verified R1/R3/R4).
// A: f32 row-major [M][lda].  B: bf16 TRANSPOSED [N][ldbt] (k fast).
// ---------------------------------------------------------------------------
struct GemmArgs {
  const float* Af;
  const unsigned short* Bt;
  float* outF;
  const float* bias;
  float* partials;
  int M, N, K;
  int lda, ldbt, ldc;
  int totSteps, nSplits;
};

enum { EPI_PARTIAL, EPI_BIAS, EPI_BF16, EPI_COST, EPI_LOSS };

template<int BM, int BN, int WR, int WC, int EPI>
DEVI void gemm_body(const GemmArgs g)
{
  constexpr int BK = 64, BKP = 72;
  constexpr int NT = WR * WC * 64;
  __shared__ short As[BM * BKP];
  __shared__ short Bs[BN * BKP];

  const int m0 = blockIdx.x * BM;
  int n0 = 0, kb0 = 0, kb1 = g.K, split = 0;
  if constexpr (EPI == EPI_PARTIAL) {
    split = blockIdx.y;
    int s0 = (split * g.totSteps) / g.nSplits;
    int s1 = ((split + 1) * g.totSteps) / g.nSplits;
    kb0 = s0 * BK;
    kb1 = s1 * BK; if (kb1 > g.K) kb1 = g.K;
  } else {
    n0 = blockIdx.y * BN;
  }
  const int tid  = threadIdx.x;
  const int lane = tid & 63;
  const int wv   = tid >> 6;
  const int wr   = wv % WR;
  const int wc   = wv / WR;

  f32x4 acc[2][4];
  #pragma unroll
  for (int i = 0; i < 2; ++i)
    #pragma unroll
    for (int j = 0; j < 4; ++j) acc[i][j] = f32x4{0.f, 0.f, 0.f, 0.f};

  for (int kb = kb0; kb < kb1; kb += BK) {
    {   // stage A (f32 -> bf16)
      constexpr int NV = BM * BK / 4;
      #pragma unroll
      for (int i = 0; i < NV / NT; ++i) {
        int idx = tid + NT * i;
        int r = idx >> 4, q = idx & 15;
        int k = kb + 4 * q;
        f32x4 v = f32x4{0.f, 0.f, 0.f, 0.f};
        if (k < kb1) v = *(const f32x4*)(g.Af + (size_t)(m0 + r) * g.lda + k);
        s16x4 s;
        s.x = f2bf(v.x); s.y = f2bf(v.y); s.z = f2bf(v.z); s.w = f2bf(v.w);
        *(s16x4*)&As[r * BKP + 4 * q] = s;
      }
    }
    {   // stage B (bf16 [N][K])
      constexpr int NV = BN * BK / 8;
      #pragma unroll
      for (int i = 0; i < NV / NT; ++i) {
        int idx = tid + NT * i;
        int r = idx >> 3, q = idx & 7;
        int k = kb + 8 * q;
        s16x8 v{};
        if ((n0 + r) < g.N && k < kb1)
          v = *(const s16x8*)(g.Bt + (size_t)(n0 + r) * g.ldbt + k);
        *(s16x8*)&Bs[r * BKP + 8 * q] = v;
      }
    }
    __syncthreads();
    #pragma unroll
    for (int s = 0; s < 2; ++s) {
      const int ko = 32 * s + 8 * (lane >> 4);
      bf16x8 a0 = *(const bf16x8*)&As[(wr * 32 +      (lane & 15)) * BKP + ko];
      bf16x8 a1 = *(const bf16x8*)&As[(wr * 32 + 16 + (lane & 15)) * BKP + ko];
      #pragma unroll
      for (int fn = 0; fn < 4; ++fn) {
        bf16x8 b = *(const bf16x8*)&Bs[(wc * 64 + fn * 16 + (lane & 15)) * BKP + ko];
        acc[0][fn] = mfma16(a0, b, acc[0][fn]);
        acc[1][fn] = mfma16(a1, b, acc[1][fn]);
      }
    }
    __syncthreads();
  }

  #pragma unroll
  for (int fm = 0; fm < 2; ++fm) {
    #pragma unroll
    for (int fn = 0; fn < 4; ++fn) {
      #pragma unroll
      for (int p = 0; p < 4; ++p) {
        int gm = m0 + wr * 32 + fm * 16 + (lane >> 4) * 4 + p;
        int gn = n0 + wc * 64 + fn * 16 + (lane & 15);
        float v = acc[fm][fn][p];
        if constexpr (EPI == EPI_PARTIAL) {
          g.partials[((size_t)split * g.M + gm) * 256 + gn] = v;
        } else {
          if (gn < g.N) g.outF[(size_t)gm * g.ldc + gn] = v + g.bias[gn];
        }
      }
    }
  }
}

template<int BM, int BN, int WR, int WC, int EPI>
__global__ __launch_bounds__(WR*WC*64)
void k_gemm2(GemmArgs g0, GemmArgs g1)
{
  gemm_body<BM, BN, WR, WC, EPI>(blockIdx.z ? g1 : g0);
}

// ---------------------------------------------------------------------------
// FGW 1024^3 GEMM, 4-wave (2x2) 64x64 tile, 256 blocks (verified R3/R4).
// ---------------------------------------------------------------------------
struct FgwGemmArgs {
  const unsigned short* A;
  const unsigned short* Bt;
  unsigned short* U;
  float* cost;
  const float* f1;
  const float* f2;
  const float* cpp;
  const float* tran;
  unsigned* mx;
  float* loss;
  float* braw;
};

template<int EPI>
__global__ __launch_bounds__(256)
void k_fgw_gemm(FgwGemmArgs a)
{
  __shared__ short As[64 * 72];
  __shared__ short Bs[64 * 72];
  __shared__ float red[4];

  const int bid = blockIdx.x, tid = threadIdx.x;
  const int lane = tid & 63, wv = tid >> 6;
  const int wr = wv & 1, wc = wv >> 1;
  const int m0 = (bid >> 4) * 64, n0 = (bid & 15) * 64;

  if constexpr (EPI == EPI_COST) {
    if (bid == 0) {
      #pragma unroll
      for (int i = 0; i < 4; ++i) a.braw[tid + 256 * i] = 0.f;
    }
  }

  f32x4 acc[2][2];
  #pragma unroll
  for (int i = 0; i < 2; ++i)
    #pragma unroll
    for (int j = 0; j < 2; ++j) acc[i][j] = f32x4{0.f, 0.f, 0.f, 0.f};

  for (int kb = 0; kb < 1024; kb += 64) {
    #pragma unroll
    for (int i = 0; i < 2; ++i) {
      int idx = tid + 256 * i;
      int r = idx >> 3, q = idx & 7;
      *(s16x8*)&As[r * 72 + 8 * q] = *(const s16x8*)&a.A [(size_t)(m0 + r) * 1024 + kb + 8 * q];
      *(s16x8*)&Bs[r * 72 + 8 * q] = *(const s16x8*)&a.Bt[(size_t)(n0 + r) * 1024 + kb + 8 * q];
    }
    __syncthreads();
    #pragma unroll
    for (int s = 0; s < 2; ++s) {
      const int ko = 32 * s + 8 * (lane >> 4);
      bf16x8 a0 = *(const bf16x8*)&As[(wr * 32 +      (lane & 15)) * 72 + ko];
      bf16x8 a1 = *(const bf16x8*)&As[(wr * 32 + 16 + (lane & 15)) * 72 + ko];
      bf16x8 b0 = *(const bf16x8*)&Bs[(wc * 32 +      (lane & 15)) * 72 + ko];
      bf16x8 b1 = *(const bf16x8*)&Bs[(wc * 32 + 16 + (lane & 15)) * 72 + ko];
      acc[0][0] = mfma16(a0, b0, acc[0][0]);
      acc[1][0] = mfma16(a1, b0, acc[1][0]);
      acc[0][1] = mfma16(a0, b1, acc[0][1]);
      acc[1][1] = mfma16(a1, b1, acc[1][1]);
    }
    __syncthreads();
  }

  float lred = 0.f;
  #pragma unroll
  for (int fm = 0; fm < 2; ++fm) {
    #pragma unroll
    for (int fn = 0; fn < 2; ++fn) {
      #pragma unroll
      for (int p = 0; p < 4; ++p) {
        int gm = m0 + wr * 32 + fm * 16 + (lane >> 4) * 4 + p;
        int gn = n0 + wc * 32 + fn * 16 + (lane & 15);
        float v = acc[fm][fn][p];
        size_t o = (size_t)gm * 1024 + gn;
        if constexpr (EPI == EPI_BF16) {
          a.U[o] = (unsigned short)f2bf(v);
        } else {
          float c = 0.1f * (a.f1[gm] + a.f2[gn] - 2.f * v) + 0.9f * a.cpp[o];
          if constexpr (EPI == EPI_COST) {
            a.cost[o] = c;
            lred = fmaxf(lred, fabsf(c));
          } else {
            lred += c * a.tran[o];
          }
        }
      }
    }
  }
  if constexpr (EPI != EPI_BF16) {
    #pragma unroll
    for (int off = 32; off; off >>= 1) {
      float t = __shfl_xor(lred, off, 64);
      lred = (EPI == EPI_COST) ? fmaxf(lred, t) : (lred + t);
    }
    if (lane == 0) red[wv] = lred;
    __syncthreads();
    if (tid == 0) {
      if constexpr (EPI == EPI_COST) {
        float t = fmaxf(fmaxf(red[0], red[1]), fmaxf(red[2], red[3]));
        atomicMax(a.mx, __float_as_uint(t));
      } else {
        atomicAdd(a.loss, red[0] + red[1] + red[2] + red[3]);
      }
    }
  }
}

// ---------------------------------------------------------------------------
// Distance via MFMA expanded form.
// featprep: F[i] = [mu_i, exp(.5 lv_i)] bf16 (128), n[i] = sum(rounded^2) f32.
// ---------------------------------------------------------------------------
struct FP {
  const float* mu[2]; const float* lv[2];
  unsigned short* F[2]; float* n[2];
};
__global__ __launch_bounds__(64)
void k_featprep(FP a)
{
  const int y = blockIdx.y;
  const int i = blockIdx.x;
  const int t = threadIdx.x;                  // 64
  float v0 = a.mu[y][(size_t)i * 64 + t];
  float v1 = expf(0.5f * a.lv[y][(size_t)i * 64 + t]);
  unsigned short u0 = (unsigned short)f2bf(v0);
  unsigned short u1 = (unsigned short)f2bf(v1);
  unsigned short* Fr = a.F[y] + (size_t)i * 128;
  Fr[t] = u0;
  Fr[64 + t] = u1;
  float r0 = bf2f(u0), r1 = bf2f(u1);
  float p = r0 * r0 + r1 * r1;
  #pragma unroll
  for (int o = 32; o; o >>= 1) p += __shfl_xor(p, o, 64);
  if (t == 0) a.n[y][i] = p;
}

// distmm: out[m][n] = nx[m] + ny[n] - 2*sum_k Fx[m][k]*Fy[n][k] + 1e-6
// z=0: cpost (bf16) + f1; z=1: cprior (bf16) + f2; z=2: cpp (f32).
struct DistMMArgs {
  const unsigned short* Fx[3]; const unsigned short* Fy[3];
  const float* nx[3]; const float* ny[3];
  unsigned short* outB[2]; float* outF; float* frow[2];
};
__global__ __launch_bounds__(256)
void k_distmm(DistMMArgs a)
{
  __shared__ short As[64 * 72];
  __shared__ short Bs[64 * 72];
  const int z = blockIdx.y;
  const int bid = blockIdx.x, tid = threadIdx.x;
  const int lane = tid & 63, wv = tid >> 6;
  const int wr = wv & 1, wc = wv >> 1;
  const int m0 = (bid >> 4) * 64, n0 = (bid & 15) * 64;
  const unsigned short* X = a.Fx[z];
  const unsigned short* Y = a.Fy[z];

  f32x4 acc[2][2];
  #pragma unroll
  for (int i = 0; i < 2; ++i)
    #pragma unroll
    for (int j = 0; j < 2; ++j) acc[i][j] = f32x4{0.f, 0.f, 0.f, 0.f};

  #pragma unroll
  for (int kb = 0; kb < 128; kb += 64) {
    #pragma unroll
    for (int i = 0; i < 2; ++i) {
      int idx = tid + 256 * i;
      int r = idx >> 3, q = idx & 7;
      *(s16x8*)&As[r * 72 + 8 * q] = *(const s16x8*)&X[(size_t)(m0 + r) * 128 + kb + 8 * q];
      *(s16x8*)&Bs[r * 72 + 8 * q] = *(const s16x8*)&Y[(size_t)(n0 + r) * 128 + kb + 8 * q];
    }
    __syncthreads();
    #pragma unroll
    for (int s = 0; s < 2; ++s) {
      const int ko = 32 * s + 8 * (lane >> 4);
      bf16x8 a0 = *(const bf16x8*)&As[(wr * 32 +      (lane & 15)) * 72 + ko];
      bf16x8 a1 = *(const bf16x8*)&As[(wr * 32 + 16 + (lane & 15)) * 72 + ko];
      bf16x8 b0 = *(const bf16x8*)&Bs[(wc * 32 +      (lane & 15)) * 72 + ko];
      bf16x8 b1 = *(const bf16x8*)&Bs[(wc * 32 + 16 + (lane & 15)) * 72 + ko];
      acc[0][0] = mfma16(a0, b0, acc[0][0]);
      acc[1][0] = mfma16(a1, b0, acc[1][0]);
      acc[0][1] = mfma16(a0, b1, acc[0][1]);
      acc[1][1] = mfma16(a1, b1, acc[1][1]);
    }
    __syncthreads();
  }

  const float* nxp = a.nx[z];
  const float* nyp = a.ny[z];
  float rp[2][4];
  #pragma unroll
  for (int fm = 0; fm < 2; ++fm)
    #pragma unroll
    for (int p = 0; p < 4; ++p) rp[fm][p] = 0.f;

  #pragma unroll
  for (int fm = 0; fm < 2; ++fm) {
    #pragma unroll
    for (int fn = 0; fn < 2; ++fn) {
      #pragma unroll
      for (int p = 0; p < 4; ++p) {
        int gm = m0 + wr * 32 + fm * 16 + (lane >> 4) * 4 + p;
        int gn = n0 + wc * 32 + fn * 16 + (lane & 15);
        float val = nxp[gm] + nyp[gn] - 2.f * acc[fm][fn][p] + 1e-6f;
        if (z == 2) a.outF[(size_t)gm * 1024 + gn] = val;
        else {
          a.outB[z][(size_t)gm * 1024 + gn] = (unsigned short)f2bf(val);
          rp[fm][p] += val * val;
        }
      }
    }
  }
  if (z < 2) {
    // reduce over the 16 lanes sharing a row group (lane&15 = col)
    #pragma unroll
    for (int fm = 0; fm < 2; ++fm)
      #pragma unroll
      for (int p = 0; p < 4; ++p) {
        float v = rp[fm][p];
        v += __shfl_xor(v, 1, 64);
        v += __shfl_xor(v, 2, 64);
        v += __shfl_xor(v, 4, 64);
        v += __shfl_xor(v, 8, 64);
        rp[fm][p] = v;
      }
    if ((lane & 15) == 0) {
      #pragma unroll
      for (int fm = 0; fm < 2; ++fm)
        #pragma unroll
        for (int p = 0; p < 4; ++p) {
          int gm = m0 + wr * 32 + fm * 16 + (lane >> 4) * 4 + p;
          atomicAdd(&a.frow[z][gm], rp[fm][p] * (1.f / 1024.f));
        }
    }
  }
}

// ---------------------------------------------------------------------------
// kbuild: K = exp(-cost/mx)*tran, KT, and braw[c] += sum_r K[r][c]*(ps/draw[r])
// ---------------------------------------------------------------------------
__global__ __launch_bounds__(256)
void k_kbuild(const float* cost, const float* tran, const unsigned* mxbits,
              const float* draw, float* braw, float* K, float* KT)
{
  __shared__ float t[64 * 65];
  __shared__ float dualS[64];
  __shared__ float csum[4][64];
  const int r0 = blockIdx.x * 64, c0 = blockIdx.y * 64;
  const int tid = threadIdx.x;
  const float inv = 1.f / __uint_as_float(*mxbits);
  const float PS = 1.f / 1024.f;
  if (tid < 64) dualS[tid] = PS / draw[r0 + tid];
  __syncthreads();
  float colpart = 0.f;
  #pragma unroll
  for (int i = 0; i < 16; ++i) {
    int idx = tid + 256 * i;
    int r = idx >> 6, c = idx & 63;
    size_t o = (size_t)(r0 + r) * 1024 + (c0 + c);
    float v = expf(-cost[o] * inv) * tran[o];
    K[o] = v;
    t[r * 65 + c] = v;
    colpart += v * dualS[r];
  }
  csum[tid >> 6][tid & 63] = colpart;
  __syncthreads();
  #pragma unroll
  for (int i = 0; i < 16; ++i) {
    int idx = tid + 256 * i;
    int c = idx >> 6, r = idx & 63;
    KT[(size_t)(c0 + c) * 1024 + (r0 + r)] = t[r * 65 + c];
  }
  if (tid < 64)
    atomicAdd(&braw[c0 + tid],
              csum[0][tid] + csum[1][tid] + csum[2][tid] + csum[3][tid]);
}

// y_raw[r] = M[r,:] . (C/x_raw)
__global__ __launch_bounds__(256)
void k_matvec(const float* M, const float* xraw, float* yraw)
{
  const int r = blockIdx.x * 4 + (threadIdx.x >> 6);
  const int lane = threadIdx.x & 63;
  const float C = 1.f / 1024.f;
  const f32x4* row = (const f32x4*)(M + (size_t)r * 1024);
  const f32x4* xv  = (const f32x4*)xraw;
  float s = 0.f;
  #pragma unroll
  for (int q = 0; q < 4; ++q) {
    f32x4 a = row[lane + 64 * q];
    f32x4 x = xv [lane + 64 * q];
    s += a.x * (C / x.x) + a.y * (C / x.y) + a.z * (C / x.z) + a.w * (C / x.w);
  }
  #pragma unroll
  for (int o = 32; o; o >>= 1) s += __shfl_xor(s, o, 64);
  if (lane == 0) yraw[r] = s;
}

// tran = (ps/draw[r])*(pt/braw[c])*K ; emit tran^T bf16; NaN-flag on last iter
__global__ __launch_bounds__(256)
void k_tranupd(const float* K, const float* draw, const float* braw,
               float* tran, unsigned short* tranT, unsigned* flag, int check)
{
  __shared__ float t[64 * 65];
  __shared__ float dualS[64], bS[64];
  const int r0 = blockIdx.x * 64, c0 = blockIdx.y * 64;
  const int tid = threadIdx.x;
  const float P = 1.f / 1024.f;
  if (tid < 64) dualS[tid] = P / draw[r0 + tid];
  else if (tid < 128) bS[tid - 64] = P / braw[c0 + tid - 64];
  __syncthreads();
  unsigned bad = 0;
  #pragma unroll
  for (int i = 0; i < 16; ++i) {
    int idx = tid + 256 * i;
    int r = idx >> 6, c = idx & 63;
    size_t o = (size_t)(r0 + r) * 1024 + (c0 + c);
    float v = dualS[r] * bS[c] * K[o];
    tran[o] = v;
    t[r * 65 + c] = v;
    if (v != v) bad = 1u;
  }
  __syncthreads();
  #pragma unroll
  for (int i = 0; i < 16; ++i) {
    int idx = tid + 256 * i;
    int c = idx >> 6, r = idx & 63;
    tranT[(size_t)(c0 + c) * 1024 + (r0 + r)] = (unsigned short)f2bf(t[r * 65 + c]);
  }
  if (check && bad) atomicOr(flag, 1u);
}

// ---------------------------------------------------------------------------
// batched f32 [R][C] -> bf16 [C][R] transpose (4 weight matrices, one launch)
// ---------------------------------------------------------------------------
struct T4 { const float* in[4]; unsigned short* out[4]; int R[4], C[4], nx[4], nt[4]; };
__global__ void k_transpose4(T4 d)
{
  __shared__ float t[64][65];
  const int z = blockIdx.y;
  const int tile = blockIdx.x;
  if (tile >= d.nt[z]) return;
  const int R = d.R[z], C = d.C[z];
  const int r0 = (tile % d.nx[z]) * 64, c0 = (tile / d.nx[z]) * 64;
  const float* in = d.in[z];
  unsigned short* out = d.out[z];
  const int tid = threadIdx.x;
  #pragma unroll
  for (int i = 0; i < 16; ++i) {
    int idx = tid + 256 * i;
    int r = idx >> 6, c = idx & 63;
    float v = 0.f;
    if ((r0 + r) < R && (c0 + c) < C) v = in[(size_t)(r0 + r) * C + (c0 + c)];
    t[r][c] = v;
  }
  __syncthreads();
  #pragma unroll
  for (int i = 0; i < 16; ++i) {
    int idx = tid + 256 * i;
    int c = idx >> 6, r = idx & 63;
    if ((c0 + c) < C && (r0 + r) < R)
      out[(size_t)(c0 + c) * R + (r0 + r)] = (unsigned short)f2bf(t[r][c]);
  }
}

// Wcomb partial reduce + transpose: WcT[v][u] = f2bf(sum_p partials[p][u][v])
__global__ void k_wcomb_reduce(const float* partials, unsigned short* WcTa,
                               unsigned short* WcTb)
{
  __shared__ float t[64][65];
  const int z = blockIdx.z;
  const float* P = partials + (size_t)z * 32 * 256 * 256;
  unsigned short* WcT = z ? WcTb : WcTa;
  const int u0 = blockIdx.x * 64, v0 = blockIdx.y * 64;
  const int tid = threadIdx.x;
  #pragma unroll
  for (int i = 0; i < 16; ++i) {
    int idx = tid + 256 * i;
    int u = idx >> 6, v = idx & 63;
    float s = 0.f;
    for (int p = 0; p < 32; ++p)
      s += P[(size_t)p * 65536 + (u0 + u) * 256 + (v0 + v)];
    t[u][v] = s;
  }
  __syncthreads();
  #pragma unroll
  for (int i = 0; i < 16; ++i) {
    int idx = tid + 256 * i;
    int v = idx >> 6, u = idx & 63;
    WcT[(size_t)(v0 + v) * 256 + (u0 + u)] = (unsigned short)f2bf(t[u][v]);
  }
}

// bc[c] = b4 . Wt1[c,:] + b1[c]
struct BcArgs {
  const float* b4[2]; const unsigned short* Wt1[2]; const float* b1[2];
  float* bc[2]; int K[2];
};
__global__ void k_bcvec(BcArgs a)
{
  const int y = blockIdx.y;
  const int c = blockIdx.x * 4 + (threadIdx.x >> 6);
  const int lane = threadIdx.x & 63;
  const int K = a.K[y];
  const unsigned short* wrow = a.Wt1[y] + (size_t)c * K;
  const float* b4 = a.b4[y];
  float s = 0.f;
  for (int k = lane * 8; k < K; k += 512) {
    s16x8 w = *(const s16x8*)&wrow[k];
    f32x4 v0 = *(const f32x4*)&b4[k];
    f32x4 v1 = *(const f32x4*)&b4[k + 4];
    s += v0.x * bf2f((unsigned short)w[0]) + v0.y * bf2f((unsigned short)w[1])
       + v0.z * bf2f((unsigned short)w[2]) + v0.w * bf2f((unsigned short)w[3])
       + v1.x * bf2f((unsigned short)w[4]) + v1.y * bf2f((unsigned short)w[5])
       + v1.z * bf2f((unsigned short)w[6]) + v1.w * bf2f((unsigned short)w[7]);
  }
  #pragma unroll
  for (int o = 32; o; o >>= 1) s += __shfl_xor(s, o, 64);
  if (lane == 0) a.bc[y][c] = s + a.b1[y][c];
}

// batched split-K reduce + bias + relu
struct Red2 { const float* partials[2]; const float* bias[2]; float* h[2]; int ns; };
__global__ void k_reduce2(Red2 a)
{
  const int y = blockIdx.y;
  int idx = blockIdx.x * 256 + threadIdx.x;
  float s = a.bias[y][idx & 255];
  const float* P = a.partials[y];
  for (int p = 0; p < a.ns; ++p) s += P[(size_t)p * (1024 * 256) + idx];
  a.h[y][idx] = fmaxf(s, 0.f);
}

// batched encoder head (2 sides)
struct EH2 {
  const float* h[2]; const float* W21[2]; const float* b21[2];
  const float* W22[2]; const float* b22[2]; const float* eps[2];
  float* mu[2]; float* lv[2]; float* zO[2];
};
__global__ void k_enc_head2(EH2 a)
{
  __shared__ float hrow[256];
  __shared__ float res[128];
  const int y = blockIdx.y;
  const int i = blockIdx.x;
  const int t = threadIdx.x;                  // 128
  hrow[t]       = a.h[y][(size_t)i * 256 + t];
  hrow[t + 128] = a.h[y][(size_t)i * 256 + t + 128];
  __syncthreads();
  const int c = t & 63;
  const float* W = (t < 64) ? a.W21[y] : a.W22[y];
  float acc = (t < 64) ? a.b21[y][c] : a.b22[y][c];
  #pragma unroll 8
  for (int j = 0; j < 256; ++j) acc += hrow[j] * W[j * 64 + c];
  res[t] = acc;
  __syncthreads();
  if (t < 64) {
    float mu = res[t], lv = res[64 + t];
    a.mu[y][(size_t)i * 64 + t] = mu;
    a.lv[y][(size_t)i * 64 + t] = lv;
    a.zO[y][(size_t)i * 64 + t] = mu + a.eps[y][(size_t)i * 64 + t] * expf(0.5f * lv);
  }
}

// fused re-encode: feature = head(relu(hd @ Wcomb + bc)) + eps reparam
struct RencArgs {
  const float* hd[2]; const unsigned short* WcT[2]; const float* bc[2];
  const float* W21[2]; const float* b21[2]; const float* W22[2]; const float* b22[2];
  const float* eps[2]; float* fout[2];
};
__global__ void k_renc_head(RencArgs a)
{
  __shared__ float hdrow[256];
  __shared__ float hr[256];
  __shared__ float res[128];
  const int y = blockIdx.y;
  const int i = blockIdx.x;
  const int t = threadIdx.x;                  // 256
  hdrow[t] = a.hd[y][(size_t)i * 256 + t];
  __syncthreads();
  {
    const s16x8* wr = (const s16x8*)(a.WcT[y] + (size_t)t * 256);
    float s = a.bc[y][t];
    #pragma unroll 4
    for (int j = 0; j < 32; ++j) {
      s16x8 w = wr[j];
      const float* hp = &hdrow[j * 8];
      s += hp[0] * bf2f((unsigned short)w[0]) + hp[1] * bf2f((unsigned short)w[1])
         + hp[2] * bf2f((unsigned short)w[2]) + hp[3] * bf2f((unsigned short)w[3])
         + hp[4] * bf2f((unsigned short)w[4]) + hp[5] * bf2f((unsigned short)w[5])
         + hp[6] * bf2f((unsigned short)w[6]) + hp[7] * bf2f((unsigned short)w[7]);
    }
    hr[t] = fmaxf(s, 0.f);
  }
  __syncthreads();
  if (t < 128) {
    const int c = t & 63;
    const float* W = (t < 64) ? a.W21[y] : a.W22[y];
    float acc = (t < 64) ? a.b21[y][c] : a.b22[y][c];
    #pragma unroll 8
    for (int j = 0; j < 256; ++j) acc += hr[j] * W[j * 64 + c];
    res[t] = acc;
  }
  __syncthreads();
  if (t < 64) {
    float mu = res[t], lv = res[64 + t];
    a.fout[y][(size_t)i * 64 + t] = mu + a.eps[y][(size_t)i * 64 + t] * expf(0.5f * lv);
  }
}

// batched decoder heads: hd = relu(z @ W3 + b3), 4 variants
struct DH4 { const float* z[4]; const float* W3[4]; const float* b3[4]; float* hd[4]; };
__global__ void k_dec_head4(DH4 a)
{
  __shared__ float zrow[64];
  const int y = blockIdx.y;
  const int i = blockIdx.x;
  const int t = threadIdx.x;                  // 256
  if (t < 64) zrow[t] = a.z[y][(size_t)i * 64 + t];
  __syncthreads();
  const float* W3 = a.W3[y];
  float acc = a.b3[y][t];
  #pragma unroll
  for (int d = 0; d < 64; ++d) acc += zrow[d] * W3[d * 256 + t];
  a.hd[y][(size_t)i * 256 + t] = fmaxf(acc, 0.f);
}

// init: tran/tranT/draw/braw/f1/f2/mx/nanflag/cyc/out-scalars
__global__ void k_init(float* tran, unsigned short* tranT, float* draw, float* braw,
                       float* f1, float* f2, unsigned* mx, unsigned* nanflag,
                       float* cyc, float* ga, float* gb, float* al)
{
  const int bid = blockIdx.x, tid = threadIdx.x;   // 1024 x 256
  const float v = 1.f / (1024.f * 1024.f);
  const unsigned short vb = (unsigned short)f2bf(v);
  const size_t base = (size_t)bid * 1024;
  #pragma unroll
  for (int i = 0; i < 4; ++i) {
    tran [base + tid + 256 * i] = v;
    tranT[base + tid + 256 * i] = vb;
  }
  if (bid == 0) {
    #pragma unroll
    for (int i = 0; i < 4; ++i) {
      int k = tid + 256 * i;
      draw[k] = 1.f; braw[k] = 0.f; f1[k] = 0.f; f2[k] = 0.f;
    }
    if (tid < 16) mx[tid] = 0u;
    if (tid == 0) { *nanflag = 0u; cyc[0] = 0.f; cyc[1] = 0.f; *ga = 0.f; *gb = 0.f; *al = 0.f; }
  }
}

__global__ void k_nanfix(float* tran, unsigned short* tranT, const unsigned* flag)
{
  if (*flag == 0u) return;
  const int bid = blockIdx.x, tid = threadIdx.x;   // 1024 x 256
  const float v = 1.f / (1024.f * 1024.f);
  const unsigned short vb = (unsigned short)f2bf(v);
  const size_t base = (size_t)bid * 1024;
  #pragma unroll
  for (int i = 0; i < 4; ++i) {
    tran [base + tid + 256 * i] = v;
    tranT[base + tid + 256 * i] = vb;
  }
}

// batched GMM KL (2 sides)
struct G2 {
  const float* z[2]; const float* mu[2]; const float* lv[2];
  const float* pmu[2]; const float* plv[2]; float* o[2];
};
__global__ void k_gmm2(G2 a)
{
  const int y = blockIdx.y;
  const int i = blockIdx.x;
  const int d = threadIdx.x;                  // 64
  const float zd = a.z[y][(size_t)i * 64 + d];
  const float m  = a.mu[y][(size_t)i * 64 + d];
  const float l  = a.lv[y][(size_t)i * 64 + d];
  float t = l + (zd - m) * (zd - m) * expf(-l);
  #pragma unroll
  for (int o = 32; o; o >>= 1) t += __shfl_xor(t, o, 64);
  const float C0 = 64.f * 1.8378770664093453f;
  float logq = -0.5f * (C0 + t);
  float lp[20];
  #pragma unroll
  for (int k = 0; k < 20; ++k) {
    float pm = a.pmu[y][k * 64 + d], pl = a.plv[y][k * 64 + d];
    float u = pl + (zd - pm) * (zd - pm) * expf(-pl);
    #pragma unroll
    for (int o = 32; o; o >>= 1) u += __shfl_xor(u, o, 64);
    lp[k] = -0.5f * (C0 + u);
  }
  float mx = lp[0];
  #pragma unroll
  for (int k = 1; k < 20; ++k) mx = fmaxf(mx, lp[k]);
  float s = 0.f;
  #pragma unroll
  for (int k = 0; k < 20; ++k) s += expf(lp[k] - mx);
  float logp = mx + logf(s) - 2.9957322735539909f;
  if (d == 0) atomicAdd(a.o[y], logq - logp);
}

struct Sq2 { const float* a[2]; const float* b[2]; float* cyc; };
__global__ void k_sqdiff2(Sq2 g)
{
  __shared__ float red[4];
  const int y = blockIdx.y;
  int idx = blockIdx.x * 256 + threadIdx.x;
  float d = g.a[y][idx] - g.b[y][idx];
  d = d * d;
  #pragma unroll
  for (int o = 32; o; o >>= 1) d += __shfl_xor(d, o, 64);
  int lane = threadIdx.x & 63, wv = threadIdx.x >> 6;
  if (lane == 0) red[wv] = d;
  __syncthreads();
  if (threadIdx.x == 0) atomicAdd(g.cyc + y, red[0] + red[1] + red[2] + red[3]);
}

__global__ void k_finish(const float* slots, float* o1, float* o2)
{
  if (threadIdx.x == 0) { *o1 = sqrtf(slots[0]); *o2 = sqrtf(slots[1]); }
}

// ---------------------------------------------------------------------------
extern "C" void kernel_launch(void* const* d_in, const int* in_sizes, int n_in,
                              void* d_out, int out_size, void* d_ws, size_t ws_size,
                              hipStream_t stream)
{
  (void)in_sizes; (void)n_in; (void)out_size; (void)ws_size;

  const float* X     = (const float*)d_in[2];
  const float* Y     = (const float*)d_in[3];
  const float* pmua  = (const float*)d_in[4];
  const float* plva  = (const float*)d_in[5];
  const float* pmub  = (const float*)d_in[6];
  const float* plvb  = (const float*)d_in[7];
  const float* epsx  = (const float*)d_in[8];
  const float* epsy  = (const float*)d_in[9];
  const float* epsxr = (const float*)d_in[10];
  const float* epsyr = (const float*)d_in[11];
  const float* W1a = (const float*)d_in[12];  const float* b1a = (const float*)d_in[13];
  const float* W21a= (const float*)d_in[14];  const float* b21a= (const float*)d_in[15];
  const float* W22a= (const float*)d_in[16];  const float* b22a= (const float*)d_in[17];
  const float* W3a = (const float*)d_in[18];  const float* b3a = (const float*)d_in[19];
  const float* W4a = (const float*)d_in[20];  const float* b4a = (const float*)d_in[21];
  const float* W1b = (const float*)d_in[22];  const float* b1b = (const float*)d_in[23];
  const float* W21b= (const float*)d_in[24];  const float* b21b= (const float*)d_in[25];
  const float* W22b= (const float*)d_in[26];  const float* b22b= (const float*)d_in[27];
  const float* W3b = (const float*)d_in[28];  const float* b3b = (const float*)d_in[29];
  const float* W4b = (const float*)d_in[30];  const float* b4b = (const float*)d_in[31];

  float* out = (float*)d_out;
  const size_t P_X = 0, P_Y = 20480000, P_X2Y = 46080000, P_Y2X = 71680000;
  const size_t Z_X = 92160000, Z_Y = 92225536;
  const size_t GMM_A = 92291072, GMM_B = 92291073;
  const size_t F_XR = 92291074, F_YR = 92356610;
  const size_t ALIGN = 92422146, CYC_X = 92422147, CYC_Y = 92422148;

  // ---- workspace carve (~82 MB)
  char* w = (char*)d_ws;
  size_t off = 0;
  auto alloc = [&](size_t bytes) -> void* {
    void* p = w + off;
    off += (bytes + 255) & ~(size_t)255;
    return p;
  };
  unsigned short* Wt1a = (unsigned short*)alloc((size_t)256 * 20000 * 2);
  unsigned short* Wt1b = (unsigned short*)alloc((size_t)256 * 25000 * 2);
  unsigned short* W4ta = (unsigned short*)alloc((size_t)20000 * 256 * 2);
  unsigned short* W4tb = (unsigned short*)alloc((size_t)25000 * 256 * 2);
  unsigned short* WcTa = (unsigned short*)alloc((size_t)256 * 256 * 2);
  unsigned short* WcTb = (unsigned short*)alloc((size_t)256 * 256 * 2);
  float* bca  = (float*)alloc(256 * 4);
  float* bcb  = (float*)alloc(256 * 4);
  float* h0   = (float*)alloc((size_t)1024 * 256 * 4);
  float* h1   = (float*)alloc((size_t)1024 * 256 * 4);
  float* mu_a = (float*)alloc(1024 * 64 * 4);
  float* lv_a = (float*)alloc(1024 * 64 * 4);
  float* mu_b = (float*)alloc(1024 * 64 * 4);
  float* lv_b = (float*)alloc(1024 * 64 * 4);
  float* f1   = (float*)alloc(1024 * 4);
  float* f2   = (float*)alloc(1024 * 4);
  unsigned* mx      = (unsigned*)alloc(16 * 4);
  unsigned* nanflag = (unsigned*)alloc(256);
  float* cyc  = (float*)alloc(256);
  float* draw = (float*)alloc(1024 * 4);
  float* braw = (float*)alloc(1024 * 4);
  unsigned short* Fb = (unsigned short*)alloc((size_t)1024 * 128 * 2);
  unsigned short* Fa = (unsigned short*)alloc((size_t)1024 * 128 * 2);
  float* nb = (float*)alloc(1024 * 4);
  float* na = (float*)alloc(1024 * 4);
  // arena (32 MB), sequentially reused:
  //   phase W: Wcomb partials (16 MB) | phase E: enc partials (32 MB)
  //   phase F: FGW matrices (28 MB)   | phase D: hdec buffers (4 MB)
  char* arena = (char*)alloc((size_t)32 * 1024 * 1024);
  float* partials = (float*)arena;
  size_t ao = 0;
  auto aalloc = [&](size_t bytes) -> void* {
    void* p = arena + ao;
    ao += (bytes + 255) & ~(size_t)255;
    return p;
  };
  unsigned short* cpostB  = (unsigned short*)aalloc((size_t)1024 * 1024 * 2);
  unsigned short* cpriorB = (unsigned short*)aalloc((size_t)1024 * 1024 * 2);
  float* cpp  = (float*)aalloc((size_t)1024 * 1024 * 4);
  float* tran = (float*)aalloc((size_t)1024 * 1024 * 4);
  unsigned short* tranT = (unsigned short*)aalloc((size_t)1024 * 1024 * 2);
  unsigned short* Umat  = (unsigned short*)aalloc((size_t)1024 * 1024 * 2);
  float* cost  = (float*)aalloc((size_t)1024 * 1024 * 4);
  float* Kmat  = (float*)aalloc((size_t)1024 * 1024 * 4);
  float* KTmat = (float*)aalloc((size_t)1024 * 1024 * 4);
  // hdec buffers alias the arena (used only after FGW is done)
  float* hd0 = (float*)(arena);
  float* hd1 = (float*)(arena + (size_t)1024 * 256 * 4);
  float* hd2 = (float*)(arena + (size_t)2 * 1024 * 256 * 4);
  float* hd3 = (float*)(arena + (size_t)3 * 1024 * 256 * 4);

  // ---- 1. weight transposes (one launch)
  {
    T4 d{};
    d.in[0] = W1a; d.out[0] = Wt1a; d.R[0] = 20000; d.C[0] = 256;
    d.in[1] = W1b; d.out[1] = Wt1b; d.R[1] = 25000; d.C[1] = 256;
    d.in[2] = W4a; d.out[2] = W4ta; d.R[2] = 256;   d.C[2] = 20000;
    d.in[3] = W4b; d.out[3] = W4tb; d.R[3] = 256;   d.C[3] = 25000;
    for (int z = 0; z < 4; ++z) {
      d.nx[z] = (d.R[z] + 63) / 64;
      d.nt[z] = d.nx[z] * ((d.C[z] + 63) / 64);
    }
    k_transpose4<<<dim3(1564, 4), 256, 0, stream>>>(d);
  }

  // ---- 2. init
  k_init<<<1024, 256, 0, stream>>>(tran, tranT, draw, braw, f1, f2, mx, nanflag,
                                   cyc, out + GMM_A, out + GMM_B, out + ALIGN);

  // ---- 3. Wcomb = W4 @ W1 (split-K) -> WcT bf16 + combined bias
  {
    GemmArgs ga{}, gb{};
    ga.Af = W4a; ga.Bt = Wt1a; ga.partials = partials;
    ga.M = 256; ga.N = 256; ga.K = 20000; ga.lda = 20000; ga.ldbt = 20000;
    ga.totSteps = 313; ga.nSplits = 32;
    gb = ga;
    gb.Af = W4b; gb.Bt = Wt1b; gb.partials = partials + (size_t)32 * 65536;
    gb.K = 25000; gb.lda = 25000; gb.ldbt = 25000; gb.totSteps = 391;
    k_gemm2<128, 256, 4, 4, EPI_PARTIAL><<<dim3(2, 32, 2), 1024, 0, stream>>>(ga, gb);
    k_wcomb_reduce<<<dim3(4, 4, 2), 256, 0, stream>>>(partials, WcTa, WcTb);
    BcArgs bc{};
    bc.b4[0] = b4a; bc.Wt1[0] = Wt1a; bc.b1[0] = b1a; bc.bc[0] = bca; bc.K[0] = 20000;
    bc.b4[1] = b4b; bc.Wt1[1] = Wt1b; bc.b1[1] = b1b; bc.bc[1] = bcb; bc.K[1] = 25000;
    k_bcvec<<<dim3(64, 2), 256, 0, stream>>>(bc);
  }

  // ---- 4. encoders (batched, 16 K-splits each)
  {
    GemmArgs ga{}, gb{};
    ga.Af = X; ga.Bt = Wt1a; ga.partials = partials;
    ga.M = 1024; ga.N = 256; ga.K = 20000; ga.lda = 20000; ga.ldbt = 20000;
    ga.totSteps = 313; ga.nSplits = 16;
    gb = ga;
    gb.Af = Y; gb.Bt = Wt1b; gb.partials = partials + (size_t)16 * 1024 * 256;
    gb.K = 25000; gb.lda = 25000; gb.ldbt = 25000; gb.totSteps = 391;
    k_gemm2<128, 256, 4, 4, EPI_PARTIAL><<<dim3(8, 16, 2), 1024, 0, stream>>>(ga, gb);
    Red2 r{};
    r.partials[0] = partials; r.partials[1] = partials + (size_t)16 * 1024 * 256;
    r.bias[0] = b1a; r.bias[1] = b1b; r.h[0] = h0; r.h[1] = h1; r.ns = 16;
    k_reduce2<<<dim3(1024, 2), 256, 0, stream>>>(r);
    EH2 e{};
    e.h[0] = h0; e.W21[0] = W21a; e.b21[0] = b21a; e.W22[0] = W22a; e.b22[0] = b22a;
    e.eps[0] = epsx; e.mu[0] = mu_a; e.lv[0] = lv_a; e.zO[0] = out + Z_X;
    e.h[1] = h1; e.W21[1] = W21b; e.b21[1] = b21b; e.W22[1] = W22b; e.b22[1] = b22b;
    e.eps[1] = epsy; e.mu[1] = mu_b; e.lv[1] = lv_b; e.zO[1] = out + Z_Y;
    k_enc_head2<<<dim3(1024, 2), 128, 0, stream>>>(e);
  }

  // ---- 5. GMM losses
  {
    G2 g{};
    g.z[0] = out + Z_X; g.mu[0] = mu_a; g.lv[0] = lv_a; g.pmu[0] = pmua; g.plv[0] = plva;
    g.o[0] = out + GMM_A;
    g.z[1] = out + Z_Y; g.mu[1] = mu_b; g.lv[1] = lv_b; g.pmu[1] = pmub; g.plv[1] = plvb;
    g.o[1] = out + GMM_B;
    k_gmm2<<<dim3(1024, 2), 64, 0, stream>>>(g);
  }

  // ---- 6. FGW(mu_b, mu_a, lv_b, lv_a) — MFMA expanded-form distances
  {
    FP fp{};
    fp.mu[0] = mu_b; fp.lv[0] = lv_b; fp.F[0] = Fb; fp.n[0] = nb;
    fp.mu[1] = mu_a; fp.lv[1] = lv_a; fp.F[1] = Fa; fp.n[1] = na;
    k_featprep<<<dim3(1024, 2), 64, 0, stream>>>(fp);
    DistMMArgs dm{};
    dm.Fx[0] = Fb; dm.Fy[0] = Fb; dm.nx[0] = nb; dm.ny[0] = nb;
    dm.Fx[1] = Fa; dm.Fy[1] = Fa; dm.nx[1] = na; dm.ny[1] = na;
    dm.Fx[2] = Fb; dm.Fy[2] = Fa; dm.nx[2] = nb; dm.ny[2] = na;
    dm.outB[0] = cpostB; dm.outB[1] = cpriorB; dm.outF = cpp;
    dm.frow[0] = f1; dm.frow[1] = f2;
    k_distmm<<<dim3(256, 3), 256, 0, stream>>>(dm);
  }
  FgwGemmArgs fg{};
  fg.f1 = f1; fg.f2 = f2; fg.cpp = cpp; fg.loss = out + ALIGN; fg.braw = braw;
  for (int it = 0; it < 10; ++it) {
    fg.A = cpostB; fg.Bt = tranT; fg.U = Umat;
    k_fgw_gemm<EPI_BF16><<<256, 256, 0, stream>>>(fg);
    fg.A = Umat; fg.Bt = cpriorB; fg.cost = cost; fg.mx = mx + it;
    k_fgw_gemm<EPI_COST><<<256, 256, 0, stream>>>(fg);
    k_kbuild<<<dim3(16, 16), 256, 0, stream>>>(cost, tran, mx + it, draw, braw, Kmat, KTmat);
    for (int r = 0; r < 5; ++r) {
      k_matvec<<<256, 256, 0, stream>>>(Kmat,  braw, draw);
      k_matvec<<<256, 256, 0, stream>>>(KTmat, draw, braw);
    }
    k_tranupd<<<dim3(16, 16), 256, 0, stream>>>(Kmat, draw, braw, tran, tranT,
                                                nanflag, it == 9 ? 1 : 0);
  }
  k_nanfix<<<1024, 256, 0, stream>>>(tran, tranT, nanflag);
  fg.A = cpostB; fg.Bt = tranT; fg.U = Umat;
  k_fgw_gemm<EPI_BF16><<<256, 256, 0, stream>>>(fg);
  fg.A = Umat; fg.Bt = cpriorB; fg.tran = tran;
  k_fgw_gemm<EPI_LOSS><<<256, 256, 0, stream>>>(fg);

  // ---- 7. decoder heads (4 in one launch; hdec aliases arena, FGW done)
  {
    DH4 d{};
    d.z[0] = out + Z_X; d.W3[0] = W3a; d.b3[0] = b3a; d.hd[0] = hd0;   // P_X
    d.z[1] = out + Z_Y; d.W3[1] = W3a; d.b3[1] = b3a; d.hd[1] = hd1;   // P_Y2X
    d.z[2] = out + Z_Y; d.W3[2] = W3b; d.b3[2] = b3b; d.hd[2] = hd2;   // P_Y
    d.z[3] = out + Z_X; d.W3[3] = W3b; d.b3[3] = b3b; d.hd[3] = hd3;   // P_X2Y
    k_dec_head4<<<dim3(1024, 4), 256, 0, stream>>>(d);
  }

  // ---- 8. fused re-encoders
  {
    RencArgs r{};
    r.hd[0] = hd3; r.WcT[0] = WcTb; r.bc[0] = bcb;                     // enc_b(dec_b(z_x))
    r.W21[0] = W21b; r.b21[0] = b21b; r.W22[0] = W22b; r.b22[0] = b22b;
    r.eps[0] = epsxr; r.fout[0] = out + F_XR;
    r.hd[1] = hd1; r.WcT[1] = WcTa; r.bc[1] = bca;                     // enc_a(dec_a(z_y))
    r.W21[1] = W21a; r.b21[1] = b21a; r.W22[1] = W22a; r.b22[1] = b22a;
    r.eps[1] = epsyr; r.fout[1] = out + F_YR;
    k_renc_head<<<dim3(1024, 2), 256, 0, stream>>>(r);
  }

  // ---- 9. cycle losses
  {
    Sq2 s{};
    s.a[0] = out + Z_X; s.b[0] = out + F_XR;
    s.a[1] = out + Z_Y; s.b[1] = out + F_YR;
    s.cyc = cyc;
    k_sqdiff2<<<dim3(256, 2), 256, 0, stream>>>(s);
    k_finish<<<1, 64, 0, stream>>>(cyc, out + CYC_X, out + CYC_Y);
  }

  // ---- 10. decoder GEMMs (pure output writes, batched by shared W4 panel)
  {
    GemmArgs ga{}, gb{};
    ga.Af = hd0; ga.Bt = W4ta; ga.outF = out + P_X; ga.bias = b4a;
    ga.M = 1024; ga.N = 20000; ga.K = 256; ga.lda = 256; ga.ldbt = 256; ga.ldc = 20000;
    gb = ga; gb.Af = hd1; gb.outF = out + P_Y2X;
    k_gemm2<128, 256, 4, 4, EPI_BIAS><<<dim3(8, 79, 2), 1024, 0, stream>>>(ga, gb);

    GemmArgs gc{}, gd{};
    gc.Af = hd2; gc.Bt = W4tb; gc.outF = out + P_Y; gc.bias = b4b;
    gc.M = 1024; gc.N = 25000; gc.K = 256; gc.lda = 256; gc.ldbt = 256; gc.ldc = 25000;
    gd = gc; gd.Af = hd3; gd.outF = out + P_X2Y;
    k_gemm2<128, 256, 4, 4, EPI_BIAS><<<dim3(8, 98, 2), 1024, 0, stream>>>(gc, gd);
  }
}